// Round 8
// baseline (662.322 us; speedup 1.0000x reference)
//
#include <hip/hip_runtime.h>
#include <hip/hip_fp16.h>
#include <hip/hip_fp8.h>
#include <math.h>

#define NB_NODES 100000
#define NB_EDGES 1600000
#define NB_GRAPHS 1000
#define CAP 160        // max nodes/graph in LDS (true max ~135; spill path beyond)
#define ECAP 2048      // LDS edge cap per graph (mean 1600; global fallback beyond)
#define NBLK1 400      // coarse pass blocks
#define CHUNK 4000     // edges per coarse block (NBLK1*CHUNK == NB_EDGES)
#define NBUCK 391      // ceil(NB_NODES/256) coarse buckets (dst >> 8)
#define BCAP 4608      // max edges per bucket (mean 4096, sigma 64, +8 sigma)
constexpr float GN_EPS = 1e-5f;

// ---- K1: per-block LDS histogram over coarse buckets + gstart (blocks 0-3) ----
__global__ __launch_bounds__(256) void k1_hist(const int* __restrict__ dst,
    int* __restrict__ hist, const int* __restrict__ batch, int* __restrict__ gstart) {
    __shared__ int h[NBUCK];
    int tid = threadIdx.x;
    for (int i = tid; i < NBUCK; i += 256) h[i] = 0;
    if (blockIdx.x < 4) {
        int g = blockIdx.x * 256 + tid;
        if (g <= NB_GRAPHS) {
            int lo = 0, hi = NB_NODES;
            while (lo < hi) {
                int mid = (lo + hi) >> 1;
                if (batch[mid] < g) lo = mid + 1; else hi = mid;
            }
            gstart[g] = lo;
        }
    }
    __syncthreads();
    int base = blockIdx.x * CHUNK;
    for (int i = tid; i < CHUNK; i += 256) atomicAdd(&h[dst[base + i] >> 8], 1);
    __syncthreads();
    for (int i = tid; i < NBUCK; i += 256) hist[blockIdx.x * NBUCK + i] = h[i];
}

// ---- K2: per bucket, exclusive scan across the 400 blocks; emit totals ----
__global__ __launch_bounds__(512) void k2a_scan(int* __restrict__ hist,
                                                int* __restrict__ total) {
    __shared__ int s[512];
    int b = blockIdx.x;  // bucket
    int tid = threadIdx.x;
    int v = (tid < NBLK1) ? hist[tid * NBUCK + b] : 0;
    s[tid] = v;
    __syncthreads();
    for (int o = 1; o < 512; o <<= 1) {
        int t = (tid >= o) ? s[tid - o] : 0;
        __syncthreads();
        s[tid] += t;
        __syncthreads();
    }
    if (tid < NBLK1) hist[tid * NBUCK + b] = s[tid] - v;  // exclusive prefix in place
    if (tid == 511) total[b] = s[511];
}

// ---- K3: scatter into bucket-contiguous runs; base recomputed in-LDS from total ----
__global__ __launch_bounds__(256) void k3_scatter(const int* __restrict__ ei,
    const int* __restrict__ hist, const int* __restrict__ total,
    unsigned int* __restrict__ ebuf) {
    __shared__ int cur[NBUCK];
    __shared__ int sc[256];
    int tid = threadIdx.x;
    int e0 = 2 * tid, e1 = 2 * tid + 1;
    int v0 = (e0 < NBUCK) ? total[e0] : 0;
    int v1 = (e1 < NBUCK) ? total[e1] : 0;
    int own = v0 + v1;
    sc[tid] = own;
    __syncthreads();
    for (int o = 1; o < 256; o <<= 1) {
        int t = (tid >= o) ? sc[tid - o] : 0;
        __syncthreads();
        sc[tid] += t;
        __syncthreads();
    }
    int pre = sc[tid] - own;
    if (e0 < NBUCK) cur[e0] = pre + hist[blockIdx.x * NBUCK + e0];
    if (e1 < NBUCK) cur[e1] = pre + v0 + hist[blockIdx.x * NBUCK + e1];
    __syncthreads();
    int eb = blockIdx.x * CHUNK;
    for (int i = tid; i < CHUNK; i += 256) {
        int e = eb + i;
        int sidx = ei[e];
        int d = ei[NB_EDGES + e];
        int pos = atomicAdd(&cur[d >> 8], 1);
        ebuf[pos] = (unsigned int)sidx | ((unsigned int)(d & 255) << 24);
    }
}

// ---- K4: per-bucket fine CSR in LDS; base recomputed in-LDS from total ----
__global__ __launch_bounds__(256) void k4_fine(const unsigned int* __restrict__ ebuf,
    const int* __restrict__ total, int* __restrict__ csr_src, int* __restrict__ rowptr,
    float* __restrict__ dinv) {
    __shared__ int arena[2 * BCAP + 768];
    unsigned int* epk = (unsigned int*)arena;
    int* outb  = arena + BCAP;
    int* cnt   = arena + 2 * BCAP;          // 256
    int* sbuf  = arena + 2 * BCAP + 256;    // 256
    int* cur2  = arena + 2 * BCAP + 512;    // 256
    int* bases = arena + 2 * BCAP;          // 392 ints, phase0 only (overlaps cnt/sbuf)
    int b = blockIdx.x;
    int tid = threadIdx.x;
    int e0 = 2 * tid, e1 = 2 * tid + 1;
    int v0 = (e0 < NBUCK) ? total[e0] : 0;
    int v1 = (e1 < NBUCK) ? total[e1] : 0;
    int own = v0 + v1;
    cur2[tid] = own;
    __syncthreads();
    for (int o = 1; o < 256; o <<= 1) {
        int t = (tid >= o) ? cur2[tid - o] : 0;
        __syncthreads();
        cur2[tid] += t;
        __syncthreads();
    }
    int pre = cur2[tid] - own;
    if (e0 < NBUCK) bases[e0] = pre;
    if (e1 < NBUCK) bases[e1] = pre + v0;
    if (tid == 0) bases[NBUCK] = NB_EDGES;
    __syncthreads();
    int eb = bases[b], ee = bases[b + 1];
    __syncthreads();  // done with bases; cnt/sbuf reusable
    int m = ee - eb;
    if (m > BCAP) m = BCAP;  // memory-safety clamp (never expected)
    for (int i = tid; i < m; i += 256) epk[i] = ebuf[eb + i];
    cnt[tid] = 0;
    __syncthreads();
    for (int i = tid; i < m; i += 256) atomicAdd(&cnt[epk[i] >> 24], 1);
    __syncthreads();
    int c = cnt[tid];
    sbuf[tid] = c;
    __syncthreads();
    for (int o = 1; o < 256; o <<= 1) {
        int t = (tid >= o) ? sbuf[tid - o] : 0;
        __syncthreads();
        sbuf[tid] += t;
        __syncthreads();
    }
    int off = sbuf[tid] - c;  // exclusive scan
    cur2[tid] = off;
    __syncthreads();
    for (int i = tid; i < m; i += 256) {
        unsigned int p = epk[i];
        int r = atomicAdd(&cur2[p >> 24], 1);
        outb[r] = (int)(p & 0x00FFFFFFu);
    }
    __syncthreads();
    for (int i = tid; i < m; i += 256) csr_src[eb + i] = outb[i];
    int node = b * 256 + tid;
    if (node < NB_NODES) {
        rowptr[node] = eb + off;
        dinv[node] = rsqrtf((float)(c + 1));
    }
    if (b == 0 && tid == 0) rowptr[NB_NODES] = NB_EDGES;
}

// ---------------- fp16 / fp8 helpers ----------------
union HU {
    uint4 u;
    __half2 h[4];
};

__device__ __forceinline__ void pkacc(__half2* a, uint4 v) {
    HU x; x.u = v;
    a[0] = __hadd2(a[0], x.h[0]);
    a[1] = __hadd2(a[1], x.h[1]);
    a[2] = __hadd2(a[2], x.h[2]);
    a[3] = __hadd2(a[3], x.h[3]);
}

// fp8 e4m3 (OCP) x8 packed in uint2 -> accumulate into 4 half2
__device__ __forceinline__ void pkacc8(__half2* a, uint2 v) {
    union { unsigned u; __hip_fp8x2_storage_t s[2]; } lo, hi;
    lo.u = v.x; hi.u = v.y;
    __half2_raw h0 = __hip_cvt_fp8x2_to_halfraw2(lo.s[0], __HIP_E4M3);
    __half2_raw h1 = __hip_cvt_fp8x2_to_halfraw2(lo.s[1], __HIP_E4M3);
    __half2_raw h2 = __hip_cvt_fp8x2_to_halfraw2(hi.s[0], __HIP_E4M3);
    __half2_raw h3 = __hip_cvt_fp8x2_to_halfraw2(hi.s[1], __HIP_E4M3);
    a[0] = __hadd2(a[0], __half2(h0));
    a[1] = __hadd2(a[1], __half2(h1));
    a[2] = __hadd2(a[2], __half2(h2));
    a[3] = __hadd2(a[3], __half2(h3));
}

__device__ __forceinline__ unsigned char f2fp8(float v) {
    return (unsigned char)__hip_cvt_float_to_fp8(v, __HIP_SATFINITE, __HIP_E4M3);
}

__device__ __forceinline__ __half2 shxor_h2(__half2 v, int m) {
    union { __half2 h; int i; } u;
    u.h = v;
    u.i = __shfl_xor(u.i, m, 64);
    return u.h;
}

// --- 64-dim aggregate core (layers 2,3), FP8 activations (round 8): row = 64B
// = ONE 64B line per edge (was 2 with fp16). R5's measurement: this gather is
// line-transaction-bound (~58G 64B-lines/s; byte/occupancy/MLP-invariant), so
// halving lines/edge is the only lever. fp8 also shrinks the table 12.8->6.4MB
// (better per-XCD L2 hit). Unpack: 4 cvt_pk_f16_fp8 + 4 pk-adds per edge-slot.
// Lane f8 holds features [f8*8, f8*8+8) as 8 fp8 (uint2).
__device__ __forceinline__ int agg4_core(const uint2* __restrict__ h8,
    const int* __restrict__ rowptr, const int* __restrict__ csr_src,
    const float* __restrict__ dinv, const float* __restrict__ bias,
    int n0, int e, int lane, int f8, int e8, float r[8]) {
    int i2 = n0 + 2 < e ? n0 + 2 : e;
    int i3 = n0 + 3 < e ? n0 + 3 : e;
    int i4 = n0 + 4 < e ? n0 + 4 : e;
    int r0 = rowptr[n0], r1 = rowptr[n0 + 1], r2 = rowptr[i2];
    int r3 = rowptr[i3], r4 = rowptr[i4];
    int d0 = r1 - r0, d1 = r2 - r1, d2 = r3 - r2, d3 = r4 - r3;
    const uint2 Z = {0u, 0u};   // fp8 0x00 == 0.0f
    int idx0 = (lane < d0) ? csr_src[r0 + lane] : -1;
    int idx1 = (lane < d1) ? csr_src[r1 + lane] : -1;
    int idx2 = (lane < d2) ? csr_src[r2 + lane] : -1;
    int idx3 = (lane < d3) ? csr_src[r3 + lane] : -1;
    uint2 self = Z;
    if (e8 < 4 && n0 + e8 < e) self = h8[(size_t)(n0 + e8) * 8 + f8];
    uint2 gA[8];
#pragma unroll
    for (int b = 0; b < 4; b++) {
        int u = __shfl(idx0, b * 8 + e8, 64);
        gA[b] = Z;
        if (u >= 0) gA[b] = h8[(size_t)u * 8 + f8];
        int v = __shfl(idx1, b * 8 + e8, 64);
        gA[4 + b] = Z;
        if (v >= 0) gA[4 + b] = h8[(size_t)v * 8 + f8];
    }
    uint2 gB[8];
#pragma unroll
    for (int b = 0; b < 4; b++) {
        int u = __shfl(idx2, b * 8 + e8, 64);
        gB[b] = Z;
        if (u >= 0) gB[b] = h8[(size_t)u * 8 + f8];
        int v = __shfl(idx3, b * 8 + e8, 64);
        gB[4 + b] = Z;
        if (v >= 0) gB[4 + b] = h8[(size_t)v * 8 + f8];
    }
    __half2 acc0[4], acc1[4], acc2[4], acc3[4];
    __half2 z2{__half(0.f), __half(0.f)};
    acc0[0] = acc0[1] = acc0[2] = acc0[3] = z2;
    acc1[0] = acc1[1] = acc1[2] = acc1[3] = z2;
    acc2[0] = acc2[1] = acc2[2] = acc2[3] = z2;
    acc3[0] = acc3[1] = acc3[2] = acc3[3] = z2;
    if (e8 == 0) pkacc8(acc0, self);
    if (e8 == 1) pkacc8(acc1, self);
    if (e8 == 2) pkacc8(acc2, self);
    if (e8 == 3) pkacc8(acc3, self);
#pragma unroll
    for (int b = 0; b < 4; b++) { pkacc8(acc0, gA[b]); pkacc8(acc1, gA[4 + b]); }
#pragma unroll
    for (int b = 0; b < 4; b++) { pkacc8(acc2, gB[b]); pkacc8(acc3, gB[4 + b]); }
    int tb0 = (d0 + 7) >> 3, tb1 = (d1 + 7) >> 3;
    int tb2 = (d2 + 7) >> 3, tb3 = (d3 + 7) >> 3;
    for (int b = 4; b < tb0 && b < 8; b++) {
        int u = __shfl(idx0, b * 8 + e8, 64);
        if (u >= 0) pkacc8(acc0, h8[(size_t)u * 8 + f8]);
    }
    for (int b = 4; b < tb1 && b < 8; b++) {
        int u = __shfl(idx1, b * 8 + e8, 64);
        if (u >= 0) pkacc8(acc1, h8[(size_t)u * 8 + f8]);
    }
    for (int b = 4; b < tb2 && b < 8; b++) {
        int u = __shfl(idx2, b * 8 + e8, 64);
        if (u >= 0) pkacc8(acc2, h8[(size_t)u * 8 + f8]);
    }
    for (int b = 4; b < tb3 && b < 8; b++) {
        int u = __shfl(idx3, b * 8 + e8, 64);
        if (u >= 0) pkacc8(acc3, h8[(size_t)u * 8 + f8]);
    }
    for (int b = 8; b < tb0; b++) {
        int j = r0 + b * 8 + e8;
        if (j < r1) pkacc8(acc0, h8[(size_t)csr_src[j] * 8 + f8]);
    }
    for (int b = 8; b < tb1; b++) {
        int j = r1 + b * 8 + e8;
        if (j < r2) pkacc8(acc1, h8[(size_t)csr_src[j] * 8 + f8]);
    }
    for (int b = 8; b < tb2; b++) {
        int j = r2 + b * 8 + e8;
        if (j < r3) pkacc8(acc2, h8[(size_t)csr_src[j] * 8 + f8]);
    }
    for (int b = 8; b < tb3; b++) {
        int j = r3 + b * 8 + e8;
        if (j < r4) pkacc8(acc3, h8[(size_t)csr_src[j] * 8 + f8]);
    }
#pragma unroll
    for (int c = 0; c < 4; c++) {
        __half2 t0 = acc0[c];
        t0 = __hadd2(t0, shxor_h2(t0, 8));
        t0 = __hadd2(t0, shxor_h2(t0, 16));
        t0 = __hadd2(t0, shxor_h2(t0, 32));
        acc0[c] = t0;
        __half2 t1 = acc1[c];
        t1 = __hadd2(t1, shxor_h2(t1, 8));
        t1 = __hadd2(t1, shxor_h2(t1, 16));
        t1 = __hadd2(t1, shxor_h2(t1, 32));
        acc1[c] = t1;
        __half2 t2 = acc2[c];
        t2 = __hadd2(t2, shxor_h2(t2, 8));
        t2 = __hadd2(t2, shxor_h2(t2, 16));
        t2 = __hadd2(t2, shxor_h2(t2, 32));
        acc2[c] = t2;
        __half2 t3 = acc3[c];
        t3 = __hadd2(t3, shxor_h2(t3, 8));
        t3 = __hadd2(t3, shxor_h2(t3, 16));
        t3 = __hadd2(t3, shxor_h2(t3, 32));
        acc3[c] = t3;
    }
    if (e8 >= 4) return -1;
    int node = n0 + e8;
    if (node >= e) return -1;
    const __half2* acc = (e8 == 0) ? acc0 : (e8 == 1) ? acc1 : (e8 == 2) ? acc2 : acc3;
    float dn = dinv[node];
    const float4* b4 = (const float4*)bias;
    float4 blo = b4[f8 * 2], bhi = b4[f8 * 2 + 1];
    float2 f0 = __half22float2(acc[0]);
    float2 f1 = __half22float2(acc[1]);
    float2 f2 = __half22float2(acc[2]);
    float2 f3 = __half22float2(acc[3]);
    r[0] = fmaf(f0.x, dn, blo.x); r[1] = fmaf(f0.y, dn, blo.y);
    r[2] = fmaf(f1.x, dn, blo.z); r[3] = fmaf(f1.y, dn, blo.w);
    r[4] = fmaf(f2.x, dn, bhi.x); r[5] = fmaf(f2.y, dn, bhi.y);
    r[6] = fmaf(f3.x, dn, bhi.z); r[7] = fmaf(f3.y, dn, bhi.w);
#pragma unroll
    for (int c = 0; c < 8; c++) r[c] = r[c] > 0.f ? r[c] : 0.f;
    return node;
}

// ---- fused aggregate + GraphNorm + 64x64 linear + dinv prescale (layer 2).
// Input fp8 rows; LDS row staging stays fp16; output written as fp8.
__device__ __forceinline__ void aggnorm_body(__half* rows, int s, int cnt, int e,
    const uint2* __restrict__ h8, const int* __restrict__ rowptr,
    const int* __restrict__ csr_src, const float* __restrict__ dinv,
    const float* __restrict__ bias, const float* __restrict__ gw,
    const float* __restrict__ gb, const float* __restrict__ ga,
    const float* __restrict__ W, unsigned char* __restrict__ out,
    float* red, float* red2, float* sam, float* ssc, float* srow) {
    int tid = threadIdx.x, lane = tid & 63, wid = tid >> 6;
    int f8 = lane & 7, e8 = lane >> 3;
    int passes = (cnt + 15) >> 4;  // 4 waves x 4 nodes per pass
    for (int p = 0; p < passes; ++p) {
        int n0 = __builtin_amdgcn_readfirstlane(s + p * 16 + wid * 4);
        if (n0 < e) {
            float r[8];
            int node = agg4_core(h8, rowptr, csr_src, dinv, bias, n0, e, lane, f8, e8, r);
            if (node >= 0) {
                HU o;
                o.h[0] = __floats2half2_rn(r[0], r[1]);
                o.h[1] = __floats2half2_rn(r[2], r[3]);
                o.h[2] = __floats2half2_rn(r[4], r[5]);
                o.h[3] = __floats2half2_rn(r[6], r[7]);
                ((uint4*)rows)[(size_t)(node - s) * 8 + f8] = o.u;
            }
        }
    }
    __syncthreads();
    float cntf = (float)(cnt > 1 ? cnt : 1);
    float sum = 0.f, sq = 0.f;
    for (int i = wid; i < cnt; i += 4) {
        float v = __half2float(rows[(size_t)i * 64 + lane]);
        sum += v;
        sq = fmaf(v, v, sq);
    }
    red[tid] = sum; red2[tid] = sq;
    __syncthreads();
    for (int st = 2; st > 0; st >>= 1) {
        if (wid < st) { red[tid] += red[tid + st * 64]; red2[tid] += red2[tid + st * 64]; }
        __syncthreads();
    }
    if (tid < 64) {
        float m = red[tid] / cntf, q = red2[tid] / cntf;
        float am = ga[tid] * m;
        sam[tid] = am;
        ssc[tid] = gw[tid] * rsqrtf(q - 2.f * am * m + am * am + GN_EPS);
    }
    __syncthreads();
    float wcol[64];
#pragma unroll
    for (int k = 0; k < 64; k++) wcol[k] = W[k * 64 + lane];
    float am = sam[lane], sc = ssc[lane], bb = gb[lane];
    for (int i = wid; i < cnt; i += 4) {
        float nv = (__half2float(rows[(size_t)i * 64 + lane]) - am) * sc + bb;
        srow[wid * 64 + lane] = nv;
        float acc = 0.f;
#pragma unroll
        for (int k = 0; k < 64; k++) acc = fmaf(srow[wid * 64 + k], wcol[k], acc);
        out[(size_t)(s + i) * 64 + lane] = f2fp8(acc * dinv[s + i]);
    }
}

__global__ __launch_bounds__(256, 4) void fused_aggnorm_k(
    const unsigned char* __restrict__ hs_in, const int* __restrict__ gstart,
    const int* __restrict__ rowptr, const int* __restrict__ csr_src,
    const float* __restrict__ dinv, const float* __restrict__ bias,
    const float* __restrict__ gw, const float* __restrict__ gb,
    const float* __restrict__ ga, const float* __restrict__ W,
    unsigned char* __restrict__ out, __half* __restrict__ spill) {
    __shared__ alignas(16) __half sA[CAP * 64];  // 20 KB
    __shared__ float red[256], red2[256];
    __shared__ float sam[64], ssc[64];
    __shared__ float srow[4 * 64];
    int g = blockIdx.x;
    int s = gstart[g], e = gstart[g + 1], cnt = e - s;
    const uint2* h8 = (const uint2*)hs_in;
    if (cnt <= CAP)
        aggnorm_body(sA, s, cnt, e, h8, rowptr, csr_src, dinv, bias,
                     gw, gb, ga, W, out, red, red2, sam, ssc, srow);
    else
        aggnorm_body(spill + (size_t)s * 64, s, cnt, e, h8, rowptr, csr_src, dinv, bias,
                     gw, gb, ga, W, out, red, red2, sam, ssc, srow);
}

// ---- fused last aggregate + mean-pool + MLP head + softmax (fp8 input) ----
__global__ __launch_bounds__(256, 4) void fused_aggpool_k(
    const unsigned char* __restrict__ hs_in, const int* __restrict__ gstart,
    const int* __restrict__ rowptr, const int* __restrict__ csr_src,
    const float* __restrict__ dinv, const float* __restrict__ bias,
    const float* __restrict__ Wd, const float* __restrict__ bd,
    const float* __restrict__ Wo, const float* __restrict__ bo,
    float* __restrict__ out) {
    __shared__ float wpart[4 * 64];
    __shared__ float sp[64];
    __shared__ float sh[64];
    __shared__ float sl[2];
    int tid = threadIdx.x, lane = tid & 63, wid = tid >> 6;
    int f8 = lane & 7, e8 = lane >> 3;
    int g = blockIdx.x;
    int s = gstart[g], e = gstart[g + 1], cnt = e - s;
    const uint2* h8 = (const uint2*)hs_in;
    float pacc[8];
#pragma unroll
    for (int j = 0; j < 8; j++) pacc[j] = 0.f;
    int passes = (cnt + 15) >> 4;
    for (int p = 0; p < passes; ++p) {
        int n0 = __builtin_amdgcn_readfirstlane(s + p * 16 + wid * 4);
        if (n0 < e) {
            float r[8];
            int node = agg4_core(h8, rowptr, csr_src, dinv, bias, n0, e, lane, f8, e8, r);
            if (node >= 0) {
#pragma unroll
                for (int j = 0; j < 8; j++) pacc[j] += r[j];
            }
        }
    }
#pragma unroll
    for (int j = 0; j < 8; j++) {
        float v = pacc[j];
        v += __shfl_xor(v, 8, 64);
        v += __shfl_xor(v, 16, 64);
        v += __shfl_xor(v, 32, 64);
        pacc[j] = v;
    }
    if (lane < 8) {
#pragma unroll
        for (int j = 0; j < 8; j++) wpart[wid * 64 + lane * 8 + j] = pacc[j];
    }
    __syncthreads();
    float cntf = (float)(cnt > 1 ? cnt : 1);
    if (tid < 64)
        sp[tid] = (wpart[tid] + wpart[64 + tid] + wpart[128 + tid] + wpart[192 + tid]) / cntf;
    __syncthreads();
    if (tid < 64) {
        float acc = bd[tid];
        for (int k = 0; k < 64; k++) acc = fmaf(sp[k], Wd[k * 64 + tid], acc);
        sh[tid] = acc > 0.f ? acc : 0.f;
    }
    __syncthreads();
    if (tid < 2) {
        float l = bo[tid];
        for (int k = 0; k < 64; k++) l = fmaf(sh[k], Wo[k * 2 + tid], l);
        sl[tid] = l;
    }
    __syncthreads();
    if (tid < 2) {
        float m = fmaxf(sl[0], sl[1]);
        float e0 = expf(sl[0] - m), e1 = expf(sl[1] - m);
        out[g * 2 + tid] = (tid == 0 ? e0 : e1) / (e0 + e1);
    }
}

// ---- layer-1 gather (16-dim), lane-per-node (R7, proven): pair owns a node;
// serial edges from LDS-staged idx; zero shuffles; y16 table L2-resident.
__device__ __forceinline__ void l1_gather(__half* rows16, int s, int cnt,
    const uint4* __restrict__ yv, const int* __restrict__ rowptr,
    const int* __restrict__ csr_src, const int* eidx, bool lds_e, int eb, int tid) {
    int f2 = tid & 1;
    uint4* r16 = (uint4*)rows16;
    for (int ln = (tid >> 1); ln < cnt; ln += 128) {
        int rb = rowptr[s + ln];
        int d = rowptr[s + ln + 1] - rb;
        HU acc;
        acc.u = yv[(size_t)(s + ln) * 2 + f2];   // self row half
        if (lds_e) {
            int o = rb - eb;
            int t = 0;
            for (; t + 4 <= d; t += 4) {
                int u0 = eidx[o + t], u1 = eidx[o + t + 1];
                int u2 = eidx[o + t + 2], u3 = eidx[o + t + 3];
                uint4 g0 = yv[(size_t)u0 * 2 + f2];
                uint4 g1 = yv[(size_t)u1 * 2 + f2];
                uint4 g2 = yv[(size_t)u2 * 2 + f2];
                uint4 g3 = yv[(size_t)u3 * 2 + f2];
                pkacc(acc.h, g0);
                pkacc(acc.h, g1);
                pkacc(acc.h, g2);
                pkacc(acc.h, g3);
            }
            for (; t < d; ++t) {
                int u = eidx[o + t];
                pkacc(acc.h, yv[(size_t)u * 2 + f2]);
            }
        } else {
            for (int t = 0; t < d; ++t) {
                int u = csr_src[rb + t];
                pkacc(acc.h, yv[(size_t)u * 2 + f2]);
            }
        }
        r16[(size_t)ln * 2 + f2] = acc.u;
    }
}

// ---- fused layer 1: gather16 -> @W1+b1+relu (+stats) -> GraphNorm1 -> @W2*dinv,
// output written as fp8 (layer-2 gather input).
__device__ __forceinline__ void l1_body(__half* rows64, __half* rows16,
    int s, int cnt,
    const uint4* __restrict__ yv, const int* __restrict__ rowptr,
    const int* __restrict__ csr_src, const int* eidx, bool lds_e, int eb,
    const float* __restrict__ dinv,
    const float* __restrict__ W1, const float* __restrict__ b1,
    const float* __restrict__ gw, const float* __restrict__ gb,
    const float* __restrict__ ga, const float* __restrict__ W2,
    unsigned char* __restrict__ out,
    float* red, float* red2, float* sam, float* ssc, float* srow) {
    int tid = threadIdx.x, lane = tid & 63, wid = tid >> 6;
    l1_gather(rows16, s, cnt, yv, rowptr, csr_src, eidx, lds_e, eb, tid);
    __syncthreads();
    // phase 2: h = relu(dot(raw16, W1col)*dinv + b1); stats over h
    float w1c[16];
#pragma unroll
    for (int k = 0; k < 16; ++k) w1c[k] = W1[k * 64 + lane];
    float bb1 = b1[lane];
    const uint4* r16v = (const uint4*)rows16;
    float cntf = (float)(cnt > 1 ? cnt : 1);
    float sum = 0.f, sq = 0.f;
    for (int i = wid; i < cnt; i += 4) {
        HU q0, q1;
        q0.u = r16v[(size_t)i * 2];
        q1.u = r16v[(size_t)i * 2 + 1];
        float dn = dinv[s + i];
        float dot = 0.f;
#pragma unroll
        for (int j = 0; j < 4; ++j) {
            float2 v = __half22float2(q0.h[j]);
            dot = fmaf(v.x, w1c[2 * j], dot);
            dot = fmaf(v.y, w1c[2 * j + 1], dot);
        }
#pragma unroll
        for (int j = 0; j < 4; ++j) {
            float2 v = __half22float2(q1.h[j]);
            dot = fmaf(v.x, w1c[8 + 2 * j], dot);
            dot = fmaf(v.y, w1c[8 + 2 * j + 1], dot);
        }
        float h = fmaf(dot, dn, bb1);
        h = h > 0.f ? h : 0.f;
        rows64[(size_t)i * 64 + lane] = __float2half(h);
        sum += h;
        sq = fmaf(h, h, sq);
    }
    red[tid] = sum; red2[tid] = sq;
    __syncthreads();
    for (int st = 2; st > 0; st >>= 1) {
        if (wid < st) { red[tid] += red[tid + st * 64]; red2[tid] += red2[tid + st * 64]; }
        __syncthreads();
    }
    if (tid < 64) {
        float m = red[tid] / cntf, q = red2[tid] / cntf;
        float am = ga[tid] * m;
        sam[tid] = am;
        ssc[tid] = gw[tid] * rsqrtf(q - 2.f * am * m + am * am + GN_EPS);
    }
    __syncthreads();
    // phase 3: norm + @W2, out = fp8((.)*dinv)
    float wcol[64];
#pragma unroll
    for (int k = 0; k < 64; k++) wcol[k] = W2[k * 64 + lane];
    float am = sam[lane], sc = ssc[lane], bbg = gb[lane];
    for (int i = wid; i < cnt; i += 4) {
        float nv = (__half2float(rows64[(size_t)i * 64 + lane]) - am) * sc + bbg;
        srow[wid * 64 + lane] = nv;
        float acc = 0.f;
#pragma unroll
        for (int k = 0; k < 64; k++) acc = fmaf(srow[wid * 64 + k], wcol[k], acc);
        out[(size_t)(s + i) * 64 + lane] = f2fp8(acc * dinv[s + i]);
    }
}

__global__ __launch_bounds__(256, 4) void fused_l1_k(
    const __half* __restrict__ y16, const int* __restrict__ gstart,
    const int* __restrict__ rowptr, const int* __restrict__ csr_src,
    const float* __restrict__ dinv, const float* __restrict__ W1,
    const float* __restrict__ b1, const float* __restrict__ gw,
    const float* __restrict__ gb, const float* __restrict__ ga,
    const float* __restrict__ W2, unsigned char* __restrict__ out,
    __half* __restrict__ spill64, __half* __restrict__ spill16) {
    __shared__ alignas(16) __half sR64[CAP * 64];  // 20 KB
    __shared__ alignas(16) __half sR16[CAP * 16];  // 5 KB
    __shared__ int arena[ECAP];                    // 8 KB (edge idx staging)
    __shared__ float red[256], red2[256];
    __shared__ float sam[64], ssc[64];
    __shared__ float srow[4 * 64];
    int tid = threadIdx.x;
    int g = blockIdx.x;
    int s = gstart[g], e = gstart[g + 1], cnt = e - s;
    int eb = rowptr[s], m = rowptr[e] - eb;
    const uint4* yv = (const uint4*)y16;
    bool lds_e = (m <= ECAP);
    if (lds_e) for (int i = tid; i < m; i += 256) arena[i] = csr_src[eb + i];
    __syncthreads();
    if (cnt <= CAP)
        l1_body(sR64, sR16, s, cnt, yv, rowptr, csr_src, arena, lds_e, eb, dinv,
                W1, b1, gw, gb, ga, W2, out, red, red2, sam, ssc, srow);
    else
        l1_body(spill64 + (size_t)s * 64, spill16 + (size_t)s * 16, s, cnt,
                yv, rowptr, csr_src, arena, lds_e, eb, dinv,
                W1, b1, gw, gb, ga, W2, out, red, red2, sam, ssc, srow);
}

// ---------------- layer0: GraphNorm(16) * dinv -> y16 [N][16] fp16 ----------------
__device__ __forceinline__ void l0_body(float* rows, int cnt, int s,
    const float* __restrict__ x, const float* __restrict__ gw,
    const float* __restrict__ gb, const float* __restrict__ ga,
    const float* __restrict__ dinv, __half* __restrict__ y16,
    float* red, float* red2, float* sstat, float* sscale, int tid) {
    int f = tid & 15, r = tid >> 4;
    float cntf = (float)(cnt > 1 ? cnt : 1);
    float sum = 0.f, sq = 0.f;
    for (int i = r; i < cnt; i += 32) {
        float v = x[(size_t)(s + i) * 16 + f];
        rows[i * 16 + f] = v;
        sum += v;
        sq = fmaf(v, v, sq);
    }
    red[tid] = sum; red2[tid] = sq;
    __syncthreads();
    for (int st = 16; st > 0; st >>= 1) {
        if (r < st) { red[tid] += red[tid + st * 16]; red2[tid] += red2[tid + st * 16]; }
        __syncthreads();
    }
    if (tid < 16) {
        float m = red[tid] / cntf, q = red2[tid] / cntf;
        float am = ga[tid] * m;
        sstat[tid] = am;
        sscale[tid] = gw[tid] * rsqrtf(q - 2.f * am * m + am * am + GN_EPS);
    }
    __syncthreads();
    float am = sstat[f], sc = sscale[f], bb = gb[f];
    for (int i = r; i < cnt; i += 32) {
        float nv = (rows[i * 16 + f] - am) * sc + bb;
        y16[(size_t)(s + i) * 16 + f] = __float2half(nv * dinv[s + i]);
    }
}

__global__ __launch_bounds__(512) void layer0_k(const float* __restrict__ x,
    const int* __restrict__ gstart, const float* __restrict__ gw,
    const float* __restrict__ gb, const float* __restrict__ ga,
    const float* __restrict__ dinv, __half* __restrict__ y16,
    float* __restrict__ spill16f) {
    __shared__ float sRows[CAP * 16];
    __shared__ float red[512], red2[512];
    __shared__ float sstat[16], sscale[16];
    int tid = threadIdx.x;
    int g = blockIdx.x;
    int s = gstart[g], e = gstart[g + 1], cnt = e - s;
    if (cnt <= CAP)
        l0_body(sRows, cnt, s, x, gw, gb, ga, dinv, y16, red, red2, sstat, sscale, tid);
    else
        l0_body(spill16f + (size_t)s * 16, cnt, s, x, gw, gb, ga, dinv, y16, red, red2, sstat, sscale, tid);
}

extern "C" void kernel_launch(void* const* d_in, const int* in_sizes, int n_in,
                              void* d_out, int out_size, void* d_ws, size_t ws_size,
                              hipStream_t stream) {
    const float* x    = (const float*)d_in[0];
    const int* ei     = (const int*)d_in[1];
    const int* batch  = (const int*)d_in[2];
    const float* gn0w = (const float*)d_in[3];
    const float* gn0b = (const float*)d_in[4];
    const float* gn0a = (const float*)d_in[5];
    const float* W1   = (const float*)d_in[6];
    const float* b1   = (const float*)d_in[7];
    const float* gn1w = (const float*)d_in[8];
    const float* gn1b = (const float*)d_in[9];
    const float* gn1a = (const float*)d_in[10];
    const float* W2   = (const float*)d_in[11];
    const float* b2   = (const float*)d_in[12];
    const float* gn2w = (const float*)d_in[13];
    const float* gn2b = (const float*)d_in[14];
    const float* gn2a = (const float*)d_in[15];
    const float* W3   = (const float*)d_in[16];
    const float* b3   = (const float*)d_in[17];
    const float* Wd   = (const float*)d_in[18];
    const float* bd   = (const float*)d_in[19];
    const float* Wo   = (const float*)d_in[20];
    const float* bo   = (const float*)d_in[21];

    char* p = (char*)d_ws;
    auto alloc = [&](size_t bytes) -> void* {
        void* r = (void*)p;
        p += (bytes + 255) & ~(size_t)255;
        return r;
    };
    unsigned char* A = (unsigned char*)alloc((size_t)NB_NODES * 64);  // fp8 activations
    unsigned char* B = (unsigned char*)alloc((size_t)NB_NODES * 64);  // fp8 activations
    __half* y16      = (__half*)alloc((size_t)NB_NODES * 16 * 2);
    int* rowptr      = (int*)alloc((size_t)(NB_NODES + 1) * 4);
    unsigned* ebuf   = (unsigned*)alloc((size_t)NB_EDGES * 4);
    int* csr_src     = (int*)alloc((size_t)NB_EDGES * 4);
    int* hist        = (int*)alloc((size_t)NBLK1 * NBUCK * 4);
    int* total       = (int*)alloc((size_t)NBUCK * 4);
    float* dinv      = (float*)alloc((size_t)NB_NODES * 4);
    int* gstart      = (int*)alloc((size_t)(NB_GRAPHS + 1) * 4);
    float* spill16f  = (float*)alloc((size_t)NB_NODES * 16 * 4);
    __half* spillH   = (__half*)alloc((size_t)NB_NODES * 64 * 2);
    __half* spillQ   = (__half*)alloc((size_t)NB_NODES * 16 * 2);

    k1_hist<<<NBLK1, 256, 0, stream>>>(ei + NB_EDGES, hist, batch, gstart);
    k2a_scan<<<NBUCK, 512, 0, stream>>>(hist, total);
    k3_scatter<<<NBLK1, 256, 0, stream>>>(ei, hist, total, ebuf);
    k4_fine<<<NBUCK, 256, 0, stream>>>(ebuf, total, csr_src, rowptr, dinv);

    layer0_k<<<NB_GRAPHS, 512, 0, stream>>>(x, gstart, gn0w, gn0b, gn0a, dinv, y16, spill16f);
    fused_l1_k<<<NB_GRAPHS, 256, 0, stream>>>(y16, gstart, rowptr, csr_src, dinv,
                                              W1, b1, gn1w, gn1b, gn1a, W2, A, spillH, spillQ);
    fused_aggnorm_k<<<NB_GRAPHS, 256, 0, stream>>>(A, gstart, rowptr, csr_src, dinv,
                                                   b2, gn2w, gn2b, gn2a, W3, B, spillH);
    fused_aggpool_k<<<NB_GRAPHS, 256, 0, stream>>>(B, gstart, rowptr, csr_src, dinv,
                                                   b3, Wd, bd, Wo, bo, (float*)d_out);
}

// Round 9
// 300.375 us; speedup vs baseline: 2.2050x; 2.2050x over previous
//
#include <hip/hip_runtime.h>
#include <hip/hip_fp16.h>
#include <math.h>

#define NB_NODES 100000
#define NB_EDGES 1600000
#define NB_GRAPHS 1000
#define CAP 160        // max nodes/graph in LDS (true max ~135; spill path beyond)
#define ECAP 2048      // LDS edge cap per graph (mean 1600; global fallback beyond)
#define NBLK1 400      // coarse pass blocks
#define CHUNK 4000     // edges per coarse block (NBLK1*CHUNK == NB_EDGES)
#define NBUCK 391      // ceil(NB_NODES/256) coarse buckets (dst >> 8)
#define BCAP 4608      // max edges per bucket (mean 4096, sigma 64, +8 sigma)
constexpr float GN_EPS = 1e-5f;

// ---- K1: per-block LDS histogram over coarse buckets + gstart (blocks 0-3) ----
__global__ __launch_bounds__(256) void k1_hist(const int* __restrict__ dst,
    int* __restrict__ hist, const int* __restrict__ batch, int* __restrict__ gstart) {
    __shared__ int h[NBUCK];
    int tid = threadIdx.x;
    for (int i = tid; i < NBUCK; i += 256) h[i] = 0;
    if (blockIdx.x < 4) {
        int g = blockIdx.x * 256 + tid;
        if (g <= NB_GRAPHS) {
            int lo = 0, hi = NB_NODES;
            while (lo < hi) {
                int mid = (lo + hi) >> 1;
                if (batch[mid] < g) lo = mid + 1; else hi = mid;
            }
            gstart[g] = lo;
        }
    }
    __syncthreads();
    int base = blockIdx.x * CHUNK;
    for (int i = tid; i < CHUNK; i += 256) atomicAdd(&h[dst[base + i] >> 8], 1);
    __syncthreads();
    for (int i = tid; i < NBUCK; i += 256) hist[blockIdx.x * NBUCK + i] = h[i];
}

// ---- K2: per bucket, exclusive scan across the 400 blocks; emit totals ----
__global__ __launch_bounds__(512) void k2a_scan(int* __restrict__ hist,
                                                int* __restrict__ total) {
    __shared__ int s[512];
    int b = blockIdx.x;  // bucket
    int tid = threadIdx.x;
    int v = (tid < NBLK1) ? hist[tid * NBUCK + b] : 0;
    s[tid] = v;
    __syncthreads();
    for (int o = 1; o < 512; o <<= 1) {
        int t = (tid >= o) ? s[tid - o] : 0;
        __syncthreads();
        s[tid] += t;
        __syncthreads();
    }
    if (tid < NBLK1) hist[tid * NBUCK + b] = s[tid] - v;  // exclusive prefix in place
    if (tid == 511) total[b] = s[511];
}

// ---- K3: scatter into bucket-contiguous runs; base recomputed in-LDS from total ----
__global__ __launch_bounds__(256) void k3_scatter(const int* __restrict__ ei,
    const int* __restrict__ hist, const int* __restrict__ total,
    unsigned int* __restrict__ ebuf) {
    __shared__ int cur[NBUCK];
    __shared__ int sc[256];
    int tid = threadIdx.x;
    int e0 = 2 * tid, e1 = 2 * tid + 1;
    int v0 = (e0 < NBUCK) ? total[e0] : 0;
    int v1 = (e1 < NBUCK) ? total[e1] : 0;
    int own = v0 + v1;
    sc[tid] = own;
    __syncthreads();
    for (int o = 1; o < 256; o <<= 1) {
        int t = (tid >= o) ? sc[tid - o] : 0;
        __syncthreads();
        sc[tid] += t;
        __syncthreads();
    }
    int pre = sc[tid] - own;
    if (e0 < NBUCK) cur[e0] = pre + hist[blockIdx.x * NBUCK + e0];
    if (e1 < NBUCK) cur[e1] = pre + v0 + hist[blockIdx.x * NBUCK + e1];
    __syncthreads();
    int eb = blockIdx.x * CHUNK;
    for (int i = tid; i < CHUNK; i += 256) {
        int e = eb + i;
        int sidx = ei[e];
        int d = ei[NB_EDGES + e];
        int pos = atomicAdd(&cur[d >> 8], 1);
        ebuf[pos] = (unsigned int)sidx | ((unsigned int)(d & 255) << 24);
    }
}

// ---- K4: per-bucket fine CSR in LDS; base recomputed in-LDS from total ----
__global__ __launch_bounds__(256) void k4_fine(const unsigned int* __restrict__ ebuf,
    const int* __restrict__ total, int* __restrict__ csr_src, int* __restrict__ rowptr,
    float* __restrict__ dinv) {
    __shared__ int arena[2 * BCAP + 768];
    unsigned int* epk = (unsigned int*)arena;
    int* outb  = arena + BCAP;
    int* cnt   = arena + 2 * BCAP;          // 256
    int* sbuf  = arena + 2 * BCAP + 256;    // 256
    int* cur2  = arena + 2 * BCAP + 512;    // 256
    int* bases = arena + 2 * BCAP;          // 392 ints, phase0 only (overlaps cnt/sbuf)
    int b = blockIdx.x;
    int tid = threadIdx.x;
    int e0 = 2 * tid, e1 = 2 * tid + 1;
    int v0 = (e0 < NBUCK) ? total[e0] : 0;
    int v1 = (e1 < NBUCK) ? total[e1] : 0;
    int own = v0 + v1;
    cur2[tid] = own;
    __syncthreads();
    for (int o = 1; o < 256; o <<= 1) {
        int t = (tid >= o) ? cur2[tid - o] : 0;
        __syncthreads();
        cur2[tid] += t;
        __syncthreads();
    }
    int pre = cur2[tid] - own;
    if (e0 < NBUCK) bases[e0] = pre;
    if (e1 < NBUCK) bases[e1] = pre + v0;
    if (tid == 0) bases[NBUCK] = NB_EDGES;
    __syncthreads();
    int eb = bases[b], ee = bases[b + 1];
    __syncthreads();  // done with bases; cnt/sbuf reusable
    int m = ee - eb;
    if (m > BCAP) m = BCAP;  // memory-safety clamp (never expected)
    for (int i = tid; i < m; i += 256) epk[i] = ebuf[eb + i];
    cnt[tid] = 0;
    __syncthreads();
    for (int i = tid; i < m; i += 256) atomicAdd(&cnt[epk[i] >> 24], 1);
    __syncthreads();
    int c = cnt[tid];
    sbuf[tid] = c;
    __syncthreads();
    for (int o = 1; o < 256; o <<= 1) {
        int t = (tid >= o) ? sbuf[tid - o] : 0;
        __syncthreads();
        sbuf[tid] += t;
        __syncthreads();
    }
    int off = sbuf[tid] - c;  // exclusive scan
    cur2[tid] = off;
    __syncthreads();
    for (int i = tid; i < m; i += 256) {
        unsigned int p = epk[i];
        int r = atomicAdd(&cur2[p >> 24], 1);
        outb[r] = (int)(p & 0x00FFFFFFu);
    }
    __syncthreads();
    for (int i = tid; i < m; i += 256) csr_src[eb + i] = outb[i];
    int node = b * 256 + tid;
    if (node < NB_NODES) {
        rowptr[node] = eb + off;
        dinv[node] = rsqrtf((float)(c + 1));
    }
    if (b == 0 && tid == 0) rowptr[NB_NODES] = NB_EDGES;
}

// ---------------- fp16 / fp8 helpers (LIBRARY-FREE, round 9) ----------------
// R8 post-mortem: ROCm __hip_cvt_* fp8 helpers caused 277MB scratch traffic
// (2x slowdown). These replacements are pure register bit-ops.
union HU {
    uint4 u;
    __half2 h[4];
};
union HF {
    unsigned u;
    __half2 h;
};

__device__ __forceinline__ void pkacc(__half2* a, uint4 v) {
    HU x; x.u = v;
    a[0] = __hadd2(a[0], x.h[0]);
    a[1] = __hadd2(a[1], x.h[1]);
    a[2] = __hadd2(a[2], x.h[2]);
    a[3] = __hadd2(a[3], x.h[3]);
}

// e4m3 byte b -> fp16 halfword (s | e4m3_bits>>1) == true_value * 2^-8.
// Exact for normals AND denormals (both mappings linear); we accumulate in the
// 2^-8-scaled domain and fold x256 into dinv at the epilogue. v_perm expands
// bytes (b1,b1,b0,b0); mask keeps (b1<<24)|(b0<<8); sign stays at bit15/31.
__device__ __forceinline__ void pkacc8(__half2* a, uint2 v) {
    HF t;
    unsigned x;
    x = __builtin_amdgcn_perm(v.x, v.x, 0x01010000u) & 0xFF00FF00u;
    t.u = (x & 0x80008000u) | ((x & 0x7f007f00u) >> 1);
    a[0] = __hadd2(a[0], t.h);
    x = __builtin_amdgcn_perm(v.x, v.x, 0x03030202u) & 0xFF00FF00u;
    t.u = (x & 0x80008000u) | ((x & 0x7f007f00u) >> 1);
    a[1] = __hadd2(a[1], t.h);
    x = __builtin_amdgcn_perm(v.y, v.y, 0x01010000u) & 0xFF00FF00u;
    t.u = (x & 0x80008000u) | ((x & 0x7f007f00u) >> 1);
    a[2] = __hadd2(a[2], t.h);
    x = __builtin_amdgcn_perm(v.y, v.y, 0x03030202u) & 0xFF00FF00u;
    t.u = (x & 0x80008000u) | ((x & 0x7f007f00u) >> 1);
    a[3] = __hadd2(a[3], t.h);
}

// float -> e4m3: clamp, scale by 2^-8 into fp16, round at bit7, extract.
__device__ __forceinline__ unsigned char f2fp8(float v) {
    v = fminf(fmaxf(v, -448.f), 448.f);
    unsigned short b = __half_as_ushort(__float2half(v * 0.00390625f));
    unsigned short em = (unsigned short)((b & 0x7fff) + 0x40);  // round-to-nearest
    return (unsigned char)(((b >> 8) & 0x80) | (em >> 7));
}

__device__ __forceinline__ __half2 shxor_h2(__half2 v, int m) {
    union { __half2 h; int i; } u;
    u.h = v;
    u.i = __shfl_xor(u.i, m, 64);
    return u.h;
}

// --- 64-dim aggregate core (layers 2,3), FP8 activations: row = 64B = ONE
// 64B line per edge (fp16 was 2). R5 measurement: gather is line-transaction
// bound (~58G 64B-lines/s; byte/occupancy/MLP-invariant) -> halving lines/edge
// is the only lever. fp8 also shrinks the table 12.8->6.4MB (better L2 hit).
// Accumulators hold values * 2^-8; epilogue uses dns = dinv*256.
__device__ __forceinline__ int agg4_core(const uint2* __restrict__ h8,
    const int* __restrict__ rowptr, const int* __restrict__ csr_src,
    const float* __restrict__ dinv, const float* __restrict__ bias,
    int n0, int e, int lane, int f8, int e8, float r[8]) {
    int i2 = n0 + 2 < e ? n0 + 2 : e;
    int i3 = n0 + 3 < e ? n0 + 3 : e;
    int i4 = n0 + 4 < e ? n0 + 4 : e;
    int r0 = rowptr[n0], r1 = rowptr[n0 + 1], r2 = rowptr[i2];
    int r3 = rowptr[i3], r4 = rowptr[i4];
    int d0 = r1 - r0, d1 = r2 - r1, d2 = r3 - r2, d3 = r4 - r3;
    const uint2 Z = {0u, 0u};   // fp8 0x00 == 0.0f
    int idx0 = (lane < d0) ? csr_src[r0 + lane] : -1;
    int idx1 = (lane < d1) ? csr_src[r1 + lane] : -1;
    int idx2 = (lane < d2) ? csr_src[r2 + lane] : -1;
    int idx3 = (lane < d3) ? csr_src[r3 + lane] : -1;
    uint2 self = Z;
    if (e8 < 4 && n0 + e8 < e) self = h8[(size_t)(n0 + e8) * 8 + f8];
    uint2 gA[8];
#pragma unroll
    for (int b = 0; b < 4; b++) {
        int u = __shfl(idx0, b * 8 + e8, 64);
        gA[b] = Z;
        if (u >= 0) gA[b] = h8[(size_t)u * 8 + f8];
        int v = __shfl(idx1, b * 8 + e8, 64);
        gA[4 + b] = Z;
        if (v >= 0) gA[4 + b] = h8[(size_t)v * 8 + f8];
    }
    uint2 gB[8];
#pragma unroll
    for (int b = 0; b < 4; b++) {
        int u = __shfl(idx2, b * 8 + e8, 64);
        gB[b] = Z;
        if (u >= 0) gB[b] = h8[(size_t)u * 8 + f8];
        int v = __shfl(idx3, b * 8 + e8, 64);
        gB[4 + b] = Z;
        if (v >= 0) gB[4 + b] = h8[(size_t)v * 8 + f8];
    }
    __half2 acc0[4], acc1[4], acc2[4], acc3[4];
    __half2 z2{__half(0.f), __half(0.f)};
    acc0[0] = acc0[1] = acc0[2] = acc0[3] = z2;
    acc1[0] = acc1[1] = acc1[2] = acc1[3] = z2;
    acc2[0] = acc2[1] = acc2[2] = acc2[3] = z2;
    acc3[0] = acc3[1] = acc3[2] = acc3[3] = z2;
    if (e8 == 0) pkacc8(acc0, self);
    if (e8 == 1) pkacc8(acc1, self);
    if (e8 == 2) pkacc8(acc2, self);
    if (e8 == 3) pkacc8(acc3, self);
#pragma unroll
    for (int b = 0; b < 4; b++) { pkacc8(acc0, gA[b]); pkacc8(acc1, gA[4 + b]); }
#pragma unroll
    for (int b = 0; b < 4; b++) { pkacc8(acc2, gB[b]); pkacc8(acc3, gB[4 + b]); }
    int tb0 = (d0 + 7) >> 3, tb1 = (d1 + 7) >> 3;
    int tb2 = (d2 + 7) >> 3, tb3 = (d3 + 7) >> 3;
    for (int b = 4; b < tb0 && b < 8; b++) {
        int u = __shfl(idx0, b * 8 + e8, 64);
        if (u >= 0) pkacc8(acc0, h8[(size_t)u * 8 + f8]);
    }
    for (int b = 4; b < tb1 && b < 8; b++) {
        int u = __shfl(idx1, b * 8 + e8, 64);
        if (u >= 0) pkacc8(acc1, h8[(size_t)u * 8 + f8]);
    }
    for (int b = 4; b < tb2 && b < 8; b++) {
        int u = __shfl(idx2, b * 8 + e8, 64);
        if (u >= 0) pkacc8(acc2, h8[(size_t)u * 8 + f8]);
    }
    for (int b = 4; b < tb3 && b < 8; b++) {
        int u = __shfl(idx3, b * 8 + e8, 64);
        if (u >= 0) pkacc8(acc3, h8[(size_t)u * 8 + f8]);
    }
    for (int b = 8; b < tb0; b++) {
        int j = r0 + b * 8 + e8;
        if (j < r1) pkacc8(acc0, h8[(size_t)csr_src[j] * 8 + f8]);
    }
    for (int b = 8; b < tb1; b++) {
        int j = r1 + b * 8 + e8;
        if (j < r2) pkacc8(acc1, h8[(size_t)csr_src[j] * 8 + f8]);
    }
    for (int b = 8; b < tb2; b++) {
        int j = r2 + b * 8 + e8;
        if (j < r3) pkacc8(acc2, h8[(size_t)csr_src[j] * 8 + f8]);
    }
    for (int b = 8; b < tb3; b++) {
        int j = r3 + b * 8 + e8;
        if (j < r4) pkacc8(acc3, h8[(size_t)csr_src[j] * 8 + f8]);
    }
#pragma unroll
    for (int c = 0; c < 4; c++) {
        __half2 t0 = acc0[c];
        t0 = __hadd2(t0, shxor_h2(t0, 8));
        t0 = __hadd2(t0, shxor_h2(t0, 16));
        t0 = __hadd2(t0, shxor_h2(t0, 32));
        acc0[c] = t0;
        __half2 t1 = acc1[c];
        t1 = __hadd2(t1, shxor_h2(t1, 8));
        t1 = __hadd2(t1, shxor_h2(t1, 16));
        t1 = __hadd2(t1, shxor_h2(t1, 32));
        acc1[c] = t1;
        __half2 t2 = acc2[c];
        t2 = __hadd2(t2, shxor_h2(t2, 8));
        t2 = __hadd2(t2, shxor_h2(t2, 16));
        t2 = __hadd2(t2, shxor_h2(t2, 32));
        acc2[c] = t2;
        __half2 t3 = acc3[c];
        t3 = __hadd2(t3, shxor_h2(t3, 8));
        t3 = __hadd2(t3, shxor_h2(t3, 16));
        t3 = __hadd2(t3, shxor_h2(t3, 32));
        acc3[c] = t3;
    }
    if (e8 >= 4) return -1;
    int node = n0 + e8;
    if (node >= e) return -1;
    const __half2* acc = (e8 == 0) ? acc0 : (e8 == 1) ? acc1 : (e8 == 2) ? acc2 : acc3;
    float dns = dinv[node] * 256.0f;   // undo the 2^-8 unpack scale once
    const float4* b4 = (const float4*)bias;
    float4 blo = b4[f8 * 2], bhi = b4[f8 * 2 + 1];
    float2 f0 = __half22float2(acc[0]);
    float2 f1 = __half22float2(acc[1]);
    float2 f2 = __half22float2(acc[2]);
    float2 f3 = __half22float2(acc[3]);
    r[0] = fmaf(f0.x, dns, blo.x); r[1] = fmaf(f0.y, dns, blo.y);
    r[2] = fmaf(f1.x, dns, blo.z); r[3] = fmaf(f1.y, dns, blo.w);
    r[4] = fmaf(f2.x, dns, bhi.x); r[5] = fmaf(f2.y, dns, bhi.y);
    r[6] = fmaf(f3.x, dns, bhi.z); r[7] = fmaf(f3.y, dns, bhi.w);
#pragma unroll
    for (int c = 0; c < 8; c++) r[c] = r[c] > 0.f ? r[c] : 0.f;
    return node;
}

// ---- fused aggregate + GraphNorm + 64x64 linear + dinv prescale (layer 2).
// Input fp8 rows; LDS row staging stays fp16; output written as fp8.
__device__ __forceinline__ void aggnorm_body(__half* rows, int s, int cnt, int e,
    const uint2* __restrict__ h8, const int* __restrict__ rowptr,
    const int* __restrict__ csr_src, const float* __restrict__ dinv,
    const float* __restrict__ bias, const float* __restrict__ gw,
    const float* __restrict__ gb, const float* __restrict__ ga,
    const float* __restrict__ W, unsigned char* __restrict__ out,
    float* red, float* red2, float* sam, float* ssc, float* srow) {
    int tid = threadIdx.x, lane = tid & 63, wid = tid >> 6;
    int f8 = lane & 7, e8 = lane >> 3;
    int passes = (cnt + 15) >> 4;  // 4 waves x 4 nodes per pass
    for (int p = 0; p < passes; ++p) {
        int n0 = __builtin_amdgcn_readfirstlane(s + p * 16 + wid * 4);
        if (n0 < e) {
            float r[8];
            int node = agg4_core(h8, rowptr, csr_src, dinv, bias, n0, e, lane, f8, e8, r);
            if (node >= 0) {
                HU o;
                o.h[0] = __floats2half2_rn(r[0], r[1]);
                o.h[1] = __floats2half2_rn(r[2], r[3]);
                o.h[2] = __floats2half2_rn(r[4], r[5]);
                o.h[3] = __floats2half2_rn(r[6], r[7]);
                ((uint4*)rows)[(size_t)(node - s) * 8 + f8] = o.u;
            }
        }
    }
    __syncthreads();
    float cntf = (float)(cnt > 1 ? cnt : 1);
    float sum = 0.f, sq = 0.f;
    for (int i = wid; i < cnt; i += 4) {
        float v = __half2float(rows[(size_t)i * 64 + lane]);
        sum += v;
        sq = fmaf(v, v, sq);
    }
    red[tid] = sum; red2[tid] = sq;
    __syncthreads();
    for (int st = 2; st > 0; st >>= 1) {
        if (wid < st) { red[tid] += red[tid + st * 64]; red2[tid] += red2[tid + st * 64]; }
        __syncthreads();
    }
    if (tid < 64) {
        float m = red[tid] / cntf, q = red2[tid] / cntf;
        float am = ga[tid] * m;
        sam[tid] = am;
        ssc[tid] = gw[tid] * rsqrtf(q - 2.f * am * m + am * am + GN_EPS);
    }
    __syncthreads();
    float wcol[64];
#pragma unroll
    for (int k = 0; k < 64; k++) wcol[k] = W[k * 64 + lane];
    float am = sam[lane], sc = ssc[lane], bb = gb[lane];
    for (int i = wid; i < cnt; i += 4) {
        float nv = (__half2float(rows[(size_t)i * 64 + lane]) - am) * sc + bb;
        srow[wid * 64 + lane] = nv;
        float acc = 0.f;
#pragma unroll
        for (int k = 0; k < 64; k++) acc = fmaf(srow[wid * 64 + k], wcol[k], acc);
        out[(size_t)(s + i) * 64 + lane] = f2fp8(acc * dinv[s + i]);
    }
}

__global__ __launch_bounds__(256, 4) void fused_aggnorm_k(
    const unsigned char* __restrict__ hs_in, const int* __restrict__ gstart,
    const int* __restrict__ rowptr, const int* __restrict__ csr_src,
    const float* __restrict__ dinv, const float* __restrict__ bias,
    const float* __restrict__ gw, const float* __restrict__ gb,
    const float* __restrict__ ga, const float* __restrict__ W,
    unsigned char* __restrict__ out, __half* __restrict__ spill) {
    __shared__ alignas(16) __half sA[CAP * 64];  // 20 KB
    __shared__ float red[256], red2[256];
    __shared__ float sam[64], ssc[64];
    __shared__ float srow[4 * 64];
    int g = blockIdx.x;
    int s = gstart[g], e = gstart[g + 1], cnt = e - s;
    const uint2* h8 = (const uint2*)hs_in;
    if (cnt <= CAP)
        aggnorm_body(sA, s, cnt, e, h8, rowptr, csr_src, dinv, bias,
                     gw, gb, ga, W, out, red, red2, sam, ssc, srow);
    else
        aggnorm_body(spill + (size_t)s * 64, s, cnt, e, h8, rowptr, csr_src, dinv, bias,
                     gw, gb, ga, W, out, red, red2, sam, ssc, srow);
}

// ---- fused last aggregate + mean-pool + MLP head + softmax (fp8 input) ----
__global__ __launch_bounds__(256, 4) void fused_aggpool_k(
    const unsigned char* __restrict__ hs_in, const int* __restrict__ gstart,
    const int* __restrict__ rowptr, const int* __restrict__ csr_src,
    const float* __restrict__ dinv, const float* __restrict__ bias,
    const float* __restrict__ Wd, const float* __restrict__ bd,
    const float* __restrict__ Wo, const float* __restrict__ bo,
    float* __restrict__ out) {
    __shared__ float wpart[4 * 64];
    __shared__ float sp[64];
    __shared__ float sh[64];
    __shared__ float sl[2];
    int tid = threadIdx.x, lane = tid & 63, wid = tid >> 6;
    int f8 = lane & 7, e8 = lane >> 3;
    int g = blockIdx.x;
    int s = gstart[g], e = gstart[g + 1], cnt = e - s;
    const uint2* h8 = (const uint2*)hs_in;
    float pacc[8];
#pragma unroll
    for (int j = 0; j < 8; j++) pacc[j] = 0.f;
    int passes = (cnt + 15) >> 4;
    for (int p = 0; p < passes; ++p) {
        int n0 = __builtin_amdgcn_readfirstlane(s + p * 16 + wid * 4);
        if (n0 < e) {
            float r[8];
            int node = agg4_core(h8, rowptr, csr_src, dinv, bias, n0, e, lane, f8, e8, r);
            if (node >= 0) {
#pragma unroll
                for (int j = 0; j < 8; j++) pacc[j] += r[j];
            }
        }
    }
#pragma unroll
    for (int j = 0; j < 8; j++) {
        float v = pacc[j];
        v += __shfl_xor(v, 8, 64);
        v += __shfl_xor(v, 16, 64);
        v += __shfl_xor(v, 32, 64);
        pacc[j] = v;
    }
    if (lane < 8) {
#pragma unroll
        for (int j = 0; j < 8; j++) wpart[wid * 64 + lane * 8 + j] = pacc[j];
    }
    __syncthreads();
    float cntf = (float)(cnt > 1 ? cnt : 1);
    if (tid < 64)
        sp[tid] = (wpart[tid] + wpart[64 + tid] + wpart[128 + tid] + wpart[192 + tid]) / cntf;
    __syncthreads();
    if (tid < 64) {
        float acc = bd[tid];
        for (int k = 0; k < 64; k++) acc = fmaf(sp[k], Wd[k * 64 + tid], acc);
        sh[tid] = acc > 0.f ? acc : 0.f;
    }
    __syncthreads();
    if (tid < 2) {
        float l = bo[tid];
        for (int k = 0; k < 64; k++) l = fmaf(sh[k], Wo[k * 2 + tid], l);
        sl[tid] = l;
    }
    __syncthreads();
    if (tid < 2) {
        float m = fmaxf(sl[0], sl[1]);
        float e0 = expf(sl[0] - m), e1 = expf(sl[1] - m);
        out[g * 2 + tid] = (tid == 0 ? e0 : e1) / (e0 + e1);
    }
}

// ---- layer-1 gather (16-dim), lane-per-node (R7, proven): pair owns a node;
// serial edges from LDS-staged idx; zero shuffles; y16 table L2-resident.
__device__ __forceinline__ void l1_gather(__half* rows16, int s, int cnt,
    const uint4* __restrict__ yv, const int* __restrict__ rowptr,
    const int* __restrict__ csr_src, const int* eidx, bool lds_e, int eb, int tid) {
    int f2 = tid & 1;
    uint4* r16 = (uint4*)rows16;
    for (int ln = (tid >> 1); ln < cnt; ln += 128) {
        int rb = rowptr[s + ln];
        int d = rowptr[s + ln + 1] - rb;
        HU acc;
        acc.u = yv[(size_t)(s + ln) * 2 + f2];   // self row half
        if (lds_e) {
            int o = rb - eb;
            int t = 0;
            for (; t + 4 <= d; t += 4) {
                int u0 = eidx[o + t], u1 = eidx[o + t + 1];
                int u2 = eidx[o + t + 2], u3 = eidx[o + t + 3];
                uint4 g0 = yv[(size_t)u0 * 2 + f2];
                uint4 g1 = yv[(size_t)u1 * 2 + f2];
                uint4 g2 = yv[(size_t)u2 * 2 + f2];
                uint4 g3 = yv[(size_t)u3 * 2 + f2];
                pkacc(acc.h, g0);
                pkacc(acc.h, g1);
                pkacc(acc.h, g2);
                pkacc(acc.h, g3);
            }
            for (; t < d; ++t) {
                int u = eidx[o + t];
                pkacc(acc.h, yv[(size_t)u * 2 + f2]);
            }
        } else {
            for (int t = 0; t < d; ++t) {
                int u = csr_src[rb + t];
                pkacc(acc.h, yv[(size_t)u * 2 + f2]);
            }
        }
        r16[(size_t)ln * 2 + f2] = acc.u;
    }
}

// ---- fused layer 1: gather16 -> @W1+b1+relu (+stats) -> GraphNorm1 -> @W2*dinv,
// output written as fp8 (layer-2 gather input).
__device__ __forceinline__ void l1_body(__half* rows64, __half* rows16,
    int s, int cnt,
    const uint4* __restrict__ yv, const int* __restrict__ rowptr,
    const int* __restrict__ csr_src, const int* eidx, bool lds_e, int eb,
    const float* __restrict__ dinv,
    const float* __restrict__ W1, const float* __restrict__ b1,
    const float* __restrict__ gw, const float* __restrict__ gb,
    const float* __restrict__ ga, const float* __restrict__ W2,
    unsigned char* __restrict__ out,
    float* red, float* red2, float* sam, float* ssc, float* srow) {
    int tid = threadIdx.x, lane = tid & 63, wid = tid >> 6;
    l1_gather(rows16, s, cnt, yv, rowptr, csr_src, eidx, lds_e, eb, tid);
    __syncthreads();
    // phase 2: h = relu(dot(raw16, W1col)*dinv + b1); stats over h
    float w1c[16];
#pragma unroll
    for (int k = 0; k < 16; ++k) w1c[k] = W1[k * 64 + lane];
    float bb1 = b1[lane];
    const uint4* r16v = (const uint4*)rows16;
    float cntf = (float)(cnt > 1 ? cnt : 1);
    float sum = 0.f, sq = 0.f;
    for (int i = wid; i < cnt; i += 4) {
        HU q0, q1;
        q0.u = r16v[(size_t)i * 2];
        q1.u = r16v[(size_t)i * 2 + 1];
        float dn = dinv[s + i];
        float dot = 0.f;
#pragma unroll
        for (int j = 0; j < 4; ++j) {
            float2 v = __half22float2(q0.h[j]);
            dot = fmaf(v.x, w1c[2 * j], dot);
            dot = fmaf(v.y, w1c[2 * j + 1], dot);
        }
#pragma unroll
        for (int j = 0; j < 4; ++j) {
            float2 v = __half22float2(q1.h[j]);
            dot = fmaf(v.x, w1c[8 + 2 * j], dot);
            dot = fmaf(v.y, w1c[8 + 2 * j + 1], dot);
        }
        float h = fmaf(dot, dn, bb1);
        h = h > 0.f ? h : 0.f;
        rows64[(size_t)i * 64 + lane] = __float2half(h);
        sum += h;
        sq = fmaf(h, h, sq);
    }
    red[tid] = sum; red2[tid] = sq;
    __syncthreads();
    for (int st = 2; st > 0; st >>= 1) {
        if (wid < st) { red[tid] += red[tid + st * 64]; red2[tid] += red2[tid + st * 64]; }
        __syncthreads();
    }
    if (tid < 64) {
        float m = red[tid] / cntf, q = red2[tid] / cntf;
        float am = ga[tid] * m;
        sam[tid] = am;
        ssc[tid] = gw[tid] * rsqrtf(q - 2.f * am * m + am * am + GN_EPS);
    }
    __syncthreads();
    // phase 3: norm + @W2, out = fp8((.)*dinv)
    float wcol[64];
#pragma unroll
    for (int k = 0; k < 64; k++) wcol[k] = W2[k * 64 + lane];
    float am = sam[lane], sc = ssc[lane], bbg = gb[lane];
    for (int i = wid; i < cnt; i += 4) {
        float nv = (__half2float(rows64[(size_t)i * 64 + lane]) - am) * sc + bbg;
        srow[wid * 64 + lane] = nv;
        float acc = 0.f;
#pragma unroll
        for (int k = 0; k < 64; k++) acc = fmaf(srow[wid * 64 + k], wcol[k], acc);
        out[(size_t)(s + i) * 64 + lane] = f2fp8(acc * dinv[s + i]);
    }
}

__global__ __launch_bounds__(256, 4) void fused_l1_k(
    const __half* __restrict__ y16, const int* __restrict__ gstart,
    const int* __restrict__ rowptr, const int* __restrict__ csr_src,
    const float* __restrict__ dinv, const float* __restrict__ W1,
    const float* __restrict__ b1, const float* __restrict__ gw,
    const float* __restrict__ gb, const float* __restrict__ ga,
    const float* __restrict__ W2, unsigned char* __restrict__ out,
    __half* __restrict__ spill64, __half* __restrict__ spill16) {
    __shared__ alignas(16) __half sR64[CAP * 64];  // 20 KB
    __shared__ alignas(16) __half sR16[CAP * 16];  // 5 KB
    __shared__ int arena[ECAP];                    // 8 KB (edge idx staging)
    __shared__ float red[256], red2[256];
    __shared__ float sam[64], ssc[64];
    __shared__ float srow[4 * 64];
    int tid = threadIdx.x;
    int g = blockIdx.x;
    int s = gstart[g], e = gstart[g + 1], cnt = e - s;
    int eb = rowptr[s], m = rowptr[e] - eb;
    const uint4* yv = (const uint4*)y16;
    bool lds_e = (m <= ECAP);
    if (lds_e) for (int i = tid; i < m; i += 256) arena[i] = csr_src[eb + i];
    __syncthreads();
    if (cnt <= CAP)
        l1_body(sR64, sR16, s, cnt, yv, rowptr, csr_src, arena, lds_e, eb, dinv,
                W1, b1, gw, gb, ga, W2, out, red, red2, sam, ssc, srow);
    else
        l1_body(spill64 + (size_t)s * 64, spill16 + (size_t)s * 16, s, cnt,
                yv, rowptr, csr_src, arena, lds_e, eb, dinv,
                W1, b1, gw, gb, ga, W2, out, red, red2, sam, ssc, srow);
}

// ---------------- layer0: GraphNorm(16) * dinv -> y16 [N][16] fp16 ----------------
__device__ __forceinline__ void l0_body(float* rows, int cnt, int s,
    const float* __restrict__ x, const float* __restrict__ gw,
    const float* __restrict__ gb, const float* __restrict__ ga,
    const float* __restrict__ dinv, __half* __restrict__ y16,
    float* red, float* red2, float* sstat, float* sscale, int tid) {
    int f = tid & 15, r = tid >> 4;
    float cntf = (float)(cnt > 1 ? cnt : 1);
    float sum = 0.f, sq = 0.f;
    for (int i = r; i < cnt; i += 32) {
        float v = x[(size_t)(s + i) * 16 + f];
        rows[i * 16 + f] = v;
        sum += v;
        sq = fmaf(v, v, sq);
    }
    red[tid] = sum; red2[tid] = sq;
    __syncthreads();
    for (int st = 16; st > 0; st >>= 1) {
        if (r < st) { red[tid] += red[tid + st * 16]; red2[tid] += red2[tid + st * 16]; }
        __syncthreads();
    }
    if (tid < 16) {
        float m = red[tid] / cntf, q = red2[tid] / cntf;
        float am = ga[tid] * m;
        sstat[tid] = am;
        sscale[tid] = gw[tid] * rsqrtf(q - 2.f * am * m + am * am + GN_EPS);
    }
    __syncthreads();
    float am = sstat[f], sc = sscale[f], bb = gb[f];
    for (int i = r; i < cnt; i += 32) {
        float nv = (rows[i * 16 + f] - am) * sc + bb;
        y16[(size_t)(s + i) * 16 + f] = __float2half(nv * dinv[s + i]);
    }
}

__global__ __launch_bounds__(512) void layer0_k(const float* __restrict__ x,
    const int* __restrict__ gstart, const float* __restrict__ gw,
    const float* __restrict__ gb, const float* __restrict__ ga,
    const float* __restrict__ dinv, __half* __restrict__ y16,
    float* __restrict__ spill16f) {
    __shared__ float sRows[CAP * 16];
    __shared__ float red[512], red2[512];
    __shared__ float sstat[16], sscale[16];
    int tid = threadIdx.x;
    int g = blockIdx.x;
    int s = gstart[g], e = gstart[g + 1], cnt = e - s;
    if (cnt <= CAP)
        l0_body(sRows, cnt, s, x, gw, gb, ga, dinv, y16, red, red2, sstat, sscale, tid);
    else
        l0_body(spill16f + (size_t)s * 16, cnt, s, x, gw, gb, ga, dinv, y16, red, red2, sstat, sscale, tid);
}

extern "C" void kernel_launch(void* const* d_in, const int* in_sizes, int n_in,
                              void* d_out, int out_size, void* d_ws, size_t ws_size,
                              hipStream_t stream) {
    const float* x    = (const float*)d_in[0];
    const int* ei     = (const int*)d_in[1];
    const int* batch  = (const int*)d_in[2];
    const float* gn0w = (const float*)d_in[3];
    const float* gn0b = (const float*)d_in[4];
    const float* gn0a = (const float*)d_in[5];
    const float* W1   = (const float*)d_in[6];
    const float* b1   = (const float*)d_in[7];
    const float* gn1w = (const float*)d_in[8];
    const float* gn1b = (const float*)d_in[9];
    const float* gn1a = (const float*)d_in[10];
    const float* W2   = (const float*)d_in[11];
    const float* b2   = (const float*)d_in[12];
    const float* gn2w = (const float*)d_in[13];
    const float* gn2b = (const float*)d_in[14];
    const float* gn2a = (const float*)d_in[15];
    const float* W3   = (const float*)d_in[16];
    const float* b3   = (const float*)d_in[17];
    const float* Wd   = (const float*)d_in[18];
    const float* bd   = (const float*)d_in[19];
    const float* Wo   = (const float*)d_in[20];
    const float* bo   = (const float*)d_in[21];

    char* p = (char*)d_ws;
    auto alloc = [&](size_t bytes) -> void* {
        void* r = (void*)p;
        p += (bytes + 255) & ~(size_t)255;
        return r;
    };
    unsigned char* A = (unsigned char*)alloc((size_t)NB_NODES * 64);  // fp8 activations
    unsigned char* B = (unsigned char*)alloc((size_t)NB_NODES * 64);  // fp8 activations
    __half* y16      = (__half*)alloc((size_t)NB_NODES * 16 * 2);
    int* rowptr      = (int*)alloc((size_t)(NB_NODES + 1) * 4);
    unsigned* ebuf   = (unsigned*)alloc((size_t)NB_EDGES * 4);
    int* csr_src     = (int*)alloc((size_t)NB_EDGES * 4);
    int* hist        = (int*)alloc((size_t)NBLK1 * NBUCK * 4);
    int* total       = (int*)alloc((size_t)NBUCK * 4);
    float* dinv      = (float*)alloc((size_t)NB_NODES * 4);
    int* gstart      = (int*)alloc((size_t)(NB_GRAPHS + 1) * 4);
    float* spill16f  = (float*)alloc((size_t)NB_NODES * 16 * 4);
    __half* spillH   = (__half*)alloc((size_t)NB_NODES * 64 * 2);
    __half* spillQ   = (__half*)alloc((size_t)NB_NODES * 16 * 2);

    k1_hist<<<NBLK1, 256, 0, stream>>>(ei + NB_EDGES, hist, batch, gstart);
    k2a_scan<<<NBUCK, 512, 0, stream>>>(hist, total);
    k3_scatter<<<NBLK1, 256, 0, stream>>>(ei, hist, total, ebuf);
    k4_fine<<<NBUCK, 256, 0, stream>>>(ebuf, total, csr_src, rowptr, dinv);

    layer0_k<<<NB_GRAPHS, 512, 0, stream>>>(x, gstart, gn0w, gn0b, gn0a, dinv, y16, spill16f);
    fused_l1_k<<<NB_GRAPHS, 256, 0, stream>>>(y16, gstart, rowptr, csr_src, dinv,
                                              W1, b1, gn1w, gn1b, gn1a, W2, A, spillH, spillQ);
    fused_aggnorm_k<<<NB_GRAPHS, 256, 0, stream>>>(A, gstart, rowptr, csr_src, dinv,
                                                   b2, gn2w, gn2b, gn2a, W3, B, spillH);
    fused_aggpool_k<<<NB_GRAPHS, 256, 0, stream>>>(B, gstart, rowptr, csr_src, dinv,
                                                   b3, Wd, bd, Wo, bo, (float*)d_out);
}

// Round 11
// 281.643 us; speedup vs baseline: 2.3516x; 1.0665x over previous
//
#include <hip/hip_runtime.h>
#include <hip/hip_fp16.h>
#include <math.h>

#define NB_NODES 100000
#define NB_EDGES 1600000
#define NB_GRAPHS 1000
#define CAP 160        // max nodes/graph in LDS (true max ~135; spill path beyond)
#define ECAP 2048      // LDS edge cap per graph (mean 1600; global fallback beyond)
#define NBLK1 400      // coarse pass blocks
#define CHUNK 4000     // edges per coarse block (NBLK1*CHUNK == NB_EDGES)
#define NBUCK 391      // ceil(NB_NODES/256) coarse buckets (dst >> 8)
#define BCAP 4608      // max edges per bucket (mean 4096, sigma 64, +8 sigma)
constexpr float GN_EPS = 1e-5f;

// ---- K1: per-block LDS histogram over coarse buckets + gstart (blocks 0-3) ----
__global__ __launch_bounds__(256) void k1_hist(const int* __restrict__ dst,
    int* __restrict__ hist, const int* __restrict__ batch, int* __restrict__ gstart) {
    __shared__ int h[NBUCK];
    int tid = threadIdx.x;
    for (int i = tid; i < NBUCK; i += 256) h[i] = 0;
    if (blockIdx.x < 4) {
        int g = blockIdx.x * 256 + tid;
        if (g <= NB_GRAPHS) {
            int lo = 0, hi = NB_NODES;
            while (lo < hi) {
                int mid = (lo + hi) >> 1;
                if (batch[mid] < g) lo = mid + 1; else hi = mid;
            }
            gstart[g] = lo;
        }
    }
    __syncthreads();
    int base = blockIdx.x * CHUNK;
    for (int i = tid; i < CHUNK; i += 256) atomicAdd(&h[dst[base + i] >> 8], 1);
    __syncthreads();
    for (int i = tid; i < NBUCK; i += 256) hist[blockIdx.x * NBUCK + i] = h[i];
}

// ---- K2: per bucket, exclusive scan across the 400 blocks; emit totals ----
__global__ __launch_bounds__(512) void k2a_scan(int* __restrict__ hist,
                                                int* __restrict__ total) {
    __shared__ int s[512];
    int b = blockIdx.x;  // bucket
    int tid = threadIdx.x;
    int v = (tid < NBLK1) ? hist[tid * NBUCK + b] : 0;
    s[tid] = v;
    __syncthreads();
    for (int o = 1; o < 512; o <<= 1) {
        int t = (tid >= o) ? s[tid - o] : 0;
        __syncthreads();
        s[tid] += t;
        __syncthreads();
    }
    if (tid < NBLK1) hist[tid * NBUCK + b] = s[tid] - v;  // exclusive prefix in place
    if (tid == 511) total[b] = s[511];
}

// ---- K3: scatter into bucket-contiguous runs; base recomputed in-LDS from total ----
__global__ __launch_bounds__(256) void k3_scatter(const int* __restrict__ ei,
    const int* __restrict__ hist, const int* __restrict__ total,
    unsigned int* __restrict__ ebuf) {
    __shared__ int cur[NBUCK];
    __shared__ int sc[256];
    int tid = threadIdx.x;
    int e0 = 2 * tid, e1 = 2 * tid + 1;
    int v0 = (e0 < NBUCK) ? total[e0] : 0;
    int v1 = (e1 < NBUCK) ? total[e1] : 0;
    int own = v0 + v1;
    sc[tid] = own;
    __syncthreads();
    for (int o = 1; o < 256; o <<= 1) {
        int t = (tid >= o) ? sc[tid - o] : 0;
        __syncthreads();
        sc[tid] += t;
        __syncthreads();
    }
    int pre = sc[tid] - own;
    if (e0 < NBUCK) cur[e0] = pre + hist[blockIdx.x * NBUCK + e0];
    if (e1 < NBUCK) cur[e1] = pre + v0 + hist[blockIdx.x * NBUCK + e1];
    __syncthreads();
    int eb = blockIdx.x * CHUNK;
    for (int i = tid; i < CHUNK; i += 256) {
        int e = eb + i;
        int sidx = ei[e];
        int d = ei[NB_EDGES + e];
        int pos = atomicAdd(&cur[d >> 8], 1);
        ebuf[pos] = (unsigned int)sidx | ((unsigned int)(d & 255) << 24);
    }
}

// ---- K4: per-bucket fine CSR in LDS; base recomputed in-LDS from total ----
__global__ __launch_bounds__(256) void k4_fine(const unsigned int* __restrict__ ebuf,
    const int* __restrict__ total, int* __restrict__ csr_src, int* __restrict__ rowptr,
    float* __restrict__ dinv) {
    __shared__ int arena[2 * BCAP + 768];
    unsigned int* epk = (unsigned int*)arena;
    int* outb  = arena + BCAP;
    int* cnt   = arena + 2 * BCAP;          // 256
    int* sbuf  = arena + 2 * BCAP + 256;    // 256
    int* cur2  = arena + 2 * BCAP + 512;    // 256
    int* bases = arena + 2 * BCAP;          // 392 ints, phase0 only (overlaps cnt/sbuf)
    int b = blockIdx.x;
    int tid = threadIdx.x;
    int e0 = 2 * tid, e1 = 2 * tid + 1;
    int v0 = (e0 < NBUCK) ? total[e0] : 0;
    int v1 = (e1 < NBUCK) ? total[e1] : 0;
    int own = v0 + v1;
    cur2[tid] = own;
    __syncthreads();
    for (int o = 1; o < 256; o <<= 1) {
        int t = (tid >= o) ? cur2[tid - o] : 0;
        __syncthreads();
        cur2[tid] += t;
        __syncthreads();
    }
    int pre = cur2[tid] - own;
    if (e0 < NBUCK) bases[e0] = pre;
    if (e1 < NBUCK) bases[e1] = pre + v0;
    if (tid == 0) bases[NBUCK] = NB_EDGES;
    __syncthreads();
    int eb = bases[b], ee = bases[b + 1];
    __syncthreads();  // done with bases; cnt/sbuf reusable
    int m = ee - eb;
    if (m > BCAP) m = BCAP;  // memory-safety clamp (never expected)
    for (int i = tid; i < m; i += 256) epk[i] = ebuf[eb + i];
    cnt[tid] = 0;
    __syncthreads();
    for (int i = tid; i < m; i += 256) atomicAdd(&cnt[epk[i] >> 24], 1);
    __syncthreads();
    int c = cnt[tid];
    sbuf[tid] = c;
    __syncthreads();
    for (int o = 1; o < 256; o <<= 1) {
        int t = (tid >= o) ? sbuf[tid - o] : 0;
        __syncthreads();
        sbuf[tid] += t;
        __syncthreads();
    }
    int off = sbuf[tid] - c;  // exclusive scan
    cur2[tid] = off;
    __syncthreads();
    for (int i = tid; i < m; i += 256) {
        unsigned int p = epk[i];
        int r = atomicAdd(&cur2[p >> 24], 1);
        outb[r] = (int)(p & 0x00FFFFFFu);
    }
    __syncthreads();
    for (int i = tid; i < m; i += 256) csr_src[eb + i] = outb[i];
    int node = b * 256 + tid;
    if (node < NB_NODES) {
        rowptr[node] = eb + off;
        dinv[node] = rsqrtf((float)(c + 1));
    }
    if (b == 0 && tid == 0) rowptr[NB_NODES] = NB_EDGES;
}

// ---------------- fp16 / fp8 helpers ----------------
// History: R8 ROCm __hip_cvt_* wrappers -> software expansion + 277MB scratch.
// R9 bit-op unpack (6 ops/half2) -> correct but VALU-bound (70us vs ~31us touch
// floor). R10 v_cvt_pk_f16_fp8 -> NOT a gfx950 instruction (compile fail).
// R11: gfx950's actual fp8->f16 convert is the MX-pipeline scalef32 family:
// v_cvt_scalef32_pk_f16_fp8 (src dword, f32 scale, word-select). Guarded by
// __has_builtin so a missing builtin degrades to the R9 bit-op path.
union HU {
    uint4 u;
    __half2 h[4];
};
union HF {
    unsigned u;
    __half2 h;
};

__device__ __forceinline__ void pkacc(__half2* a, uint4 v) {
    HU x; x.u = v;
    a[0] = __hadd2(a[0], x.h[0]);
    a[1] = __hadd2(a[1], x.h[1]);
    a[2] = __hadd2(a[2], x.h[2]);
    a[3] = __hadd2(a[3], x.h[3]);
}

#if defined(__has_builtin)
#if __has_builtin(__builtin_amdgcn_cvt_scalef32_pk_f16_fp8)
#define FP8_NATIVE 1
#endif
#endif

#ifdef FP8_NATIVE
// Native: 1 VOP per half2, true values (scale = 1.0), word-select constant.
typedef _Float16 f16x2v __attribute__((ext_vector_type(2)));
template<bool HI>
__device__ __forceinline__ __half2 cvt2_fp8(unsigned x) {
    union { f16x2v f; __half2 h; } u;
    u.f = __builtin_amdgcn_cvt_scalef32_pk_f16_fp8(x, 1.0f, HI);
    return u.h;
}
__device__ __forceinline__ void pkacc8(__half2* a, uint2 v) {
    a[0] = __hadd2(a[0], cvt2_fp8<false>(v.x));
    a[1] = __hadd2(a[1], cvt2_fp8<true >(v.x));
    a[2] = __hadd2(a[2], cvt2_fp8<false>(v.y));
    a[3] = __hadd2(a[3], cvt2_fp8<true >(v.y));
}
#define FP8_UNPACK_SCALE 1.0f
#else
// Fallback (R9, proven correct at absmax 0.0039): byte->high-halfword via
// zero-source v_perm (selector 0x0C = constant 0), then fp16 reinterpret
// == true_value * 2^-8 (exact for normals+denormals; both linear).
__device__ __forceinline__ __half2 u2h_scaled(unsigned x) {
    HF t;
    t.u = (x & 0x80008000u) | ((x & 0x7f007f00u) >> 1);
    return t.h;
}
__device__ __forceinline__ void pkacc8(__half2* a, uint2 v) {
    a[0] = __hadd2(a[0], u2h_scaled(__builtin_amdgcn_perm(0u, v.x, 0x010C000Cu)));
    a[1] = __hadd2(a[1], u2h_scaled(__builtin_amdgcn_perm(0u, v.x, 0x030C020Cu)));
    a[2] = __hadd2(a[2], u2h_scaled(__builtin_amdgcn_perm(0u, v.y, 0x010C000Cu)));
    a[3] = __hadd2(a[3], u2h_scaled(__builtin_amdgcn_perm(0u, v.y, 0x030C020Cu)));
}
#define FP8_UNPACK_SCALE 256.0f
#endif

// float -> e4m3: clamp, scale by 2^-8 into fp16, round at bit7, extract.
// (bit-op pack; epilogue-only, proven exact in R9)
__device__ __forceinline__ unsigned char f2fp8(float v) {
    v = fminf(fmaxf(v, -448.f), 448.f);
    unsigned short b = __half_as_ushort(__float2half(v * 0.00390625f));
    unsigned short em = (unsigned short)((b & 0x7fff) + 0x40);  // round-to-nearest
    return (unsigned char)(((b >> 8) & 0x80) | (em >> 7));
}

__device__ __forceinline__ __half2 shxor_h2(__half2 v, int m) {
    union { __half2 h; int i; } u;
    u.h = v;
    u.i = __shfl_xor(u.i, m, 64);
    return u.h;
}

// --- 64-dim aggregate core (layers 2,3), FP8 activations: row = 64B = ONE
// 64B line per edge (fp16 was 2). R5 measurement: the fp16 gather is
// line-transaction bound (~58G 64B-touches/s); fp8 halves touches/edge ->
// floor ~31us. Accumulators hold values * (1/FP8_UNPACK_SCALE); epilogue
// multiplies dinv by FP8_UNPACK_SCALE once per node.
__device__ __forceinline__ int agg4_core(const uint2* __restrict__ h8,
    const int* __restrict__ rowptr, const int* __restrict__ csr_src,
    const float* __restrict__ dinv, const float* __restrict__ bias,
    int n0, int e, int lane, int f8, int e8, float r[8]) {
    int i2 = n0 + 2 < e ? n0 + 2 : e;
    int i3 = n0 + 3 < e ? n0 + 3 : e;
    int i4 = n0 + 4 < e ? n0 + 4 : e;
    int r0 = rowptr[n0], r1 = rowptr[n0 + 1], r2 = rowptr[i2];
    int r3 = rowptr[i3], r4 = rowptr[i4];
    int d0 = r1 - r0, d1 = r2 - r1, d2 = r3 - r2, d3 = r4 - r3;
    const uint2 Z = {0u, 0u};   // fp8 0x00 == 0.0f
    int idx0 = (lane < d0) ? csr_src[r0 + lane] : -1;
    int idx1 = (lane < d1) ? csr_src[r1 + lane] : -1;
    int idx2 = (lane < d2) ? csr_src[r2 + lane] : -1;
    int idx3 = (lane < d3) ? csr_src[r3 + lane] : -1;
    uint2 self = Z;
    if (e8 < 4 && n0 + e8 < e) self = h8[(size_t)(n0 + e8) * 8 + f8];
    uint2 gA[8];
#pragma unroll
    for (int b = 0; b < 4; b++) {
        int u = __shfl(idx0, b * 8 + e8, 64);
        gA[b] = Z;
        if (u >= 0) gA[b] = h8[(size_t)u * 8 + f8];
        int v = __shfl(idx1, b * 8 + e8, 64);
        gA[4 + b] = Z;
        if (v >= 0) gA[4 + b] = h8[(size_t)v * 8 + f8];
    }
    uint2 gB[8];
#pragma unroll
    for (int b = 0; b < 4; b++) {
        int u = __shfl(idx2, b * 8 + e8, 64);
        gB[b] = Z;
        if (u >= 0) gB[b] = h8[(size_t)u * 8 + f8];
        int v = __shfl(idx3, b * 8 + e8, 64);
        gB[4 + b] = Z;
        if (v >= 0) gB[4 + b] = h8[(size_t)v * 8 + f8];
    }
    __half2 acc0[4], acc1[4], acc2[4], acc3[4];
    __half2 z2{__half(0.f), __half(0.f)};
    acc0[0] = acc0[1] = acc0[2] = acc0[3] = z2;
    acc1[0] = acc1[1] = acc1[2] = acc1[3] = z2;
    acc2[0] = acc2[1] = acc2[2] = acc2[3] = z2;
    acc3[0] = acc3[1] = acc3[2] = acc3[3] = z2;
    if (e8 == 0) pkacc8(acc0, self);
    if (e8 == 1) pkacc8(acc1, self);
    if (e8 == 2) pkacc8(acc2, self);
    if (e8 == 3) pkacc8(acc3, self);
#pragma unroll
    for (int b = 0; b < 4; b++) { pkacc8(acc0, gA[b]); pkacc8(acc1, gA[4 + b]); }
#pragma unroll
    for (int b = 0; b < 4; b++) { pkacc8(acc2, gB[b]); pkacc8(acc3, gB[4 + b]); }
    int tb0 = (d0 + 7) >> 3, tb1 = (d1 + 7) >> 3;
    int tb2 = (d2 + 7) >> 3, tb3 = (d3 + 7) >> 3;
    for (int b = 4; b < tb0 && b < 8; b++) {
        int u = __shfl(idx0, b * 8 + e8, 64);
        if (u >= 0) pkacc8(acc0, h8[(size_t)u * 8 + f8]);
    }
    for (int b = 4; b < tb1 && b < 8; b++) {
        int u = __shfl(idx1, b * 8 + e8, 64);
        if (u >= 0) pkacc8(acc1, h8[(size_t)u * 8 + f8]);
    }
    for (int b = 4; b < tb2 && b < 8; b++) {
        int u = __shfl(idx2, b * 8 + e8, 64);
        if (u >= 0) pkacc8(acc2, h8[(size_t)u * 8 + f8]);
    }
    for (int b = 4; b < tb3 && b < 8; b++) {
        int u = __shfl(idx3, b * 8 + e8, 64);
        if (u >= 0) pkacc8(acc3, h8[(size_t)u * 8 + f8]);
    }
    for (int b = 8; b < tb0; b++) {
        int j = r0 + b * 8 + e8;
        if (j < r1) pkacc8(acc0, h8[(size_t)csr_src[j] * 8 + f8]);
    }
    for (int b = 8; b < tb1; b++) {
        int j = r1 + b * 8 + e8;
        if (j < r2) pkacc8(acc1, h8[(size_t)csr_src[j] * 8 + f8]);
    }
    for (int b = 8; b < tb2; b++) {
        int j = r2 + b * 8 + e8;
        if (j < r3) pkacc8(acc2, h8[(size_t)csr_src[j] * 8 + f8]);
    }
    for (int b = 8; b < tb3; b++) {
        int j = r3 + b * 8 + e8;
        if (j < r4) pkacc8(acc3, h8[(size_t)csr_src[j] * 8 + f8]);
    }
#pragma unroll
    for (int c = 0; c < 4; c++) {
        __half2 t0 = acc0[c];
        t0 = __hadd2(t0, shxor_h2(t0, 8));
        t0 = __hadd2(t0, shxor_h2(t0, 16));
        t0 = __hadd2(t0, shxor_h2(t0, 32));
        acc0[c] = t0;
        __half2 t1 = acc1[c];
        t1 = __hadd2(t1, shxor_h2(t1, 8));
        t1 = __hadd2(t1, shxor_h2(t1, 16));
        t1 = __hadd2(t1, shxor_h2(t1, 32));
        acc1[c] = t1;
        __half2 t2 = acc2[c];
        t2 = __hadd2(t2, shxor_h2(t2, 8));
        t2 = __hadd2(t2, shxor_h2(t2, 16));
        t2 = __hadd2(t2, shxor_h2(t2, 32));
        acc2[c] = t2;
        __half2 t3 = acc3[c];
        t3 = __hadd2(t3, shxor_h2(t3, 8));
        t3 = __hadd2(t3, shxor_h2(t3, 16));
        t3 = __hadd2(t3, shxor_h2(t3, 32));
        acc3[c] = t3;
    }
    if (e8 >= 4) return -1;
    int node = n0 + e8;
    if (node >= e) return -1;
    const __half2* acc = (e8 == 0) ? acc0 : (e8 == 1) ? acc1 : (e8 == 2) ? acc2 : acc3;
    float dn = dinv[node] * FP8_UNPACK_SCALE;
    const float4* b4 = (const float4*)bias;
    float4 blo = b4[f8 * 2], bhi = b4[f8 * 2 + 1];
    float2 f0 = __half22float2(acc[0]);
    float2 f1 = __half22float2(acc[1]);
    float2 f2 = __half22float2(acc[2]);
    float2 f3 = __half22float2(acc[3]);
    r[0] = fmaf(f0.x, dn, blo.x); r[1] = fmaf(f0.y, dn, blo.y);
    r[2] = fmaf(f1.x, dn, blo.z); r[3] = fmaf(f1.y, dn, blo.w);
    r[4] = fmaf(f2.x, dn, bhi.x); r[5] = fmaf(f2.y, dn, bhi.y);
    r[6] = fmaf(f3.x, dn, bhi.z); r[7] = fmaf(f3.y, dn, bhi.w);
#pragma unroll
    for (int c = 0; c < 8; c++) r[c] = r[c] > 0.f ? r[c] : 0.f;
    return node;
}

// ---- fused aggregate + GraphNorm + 64x64 linear + dinv prescale (layer 2).
// Input fp8 rows; LDS row staging stays fp16; output written as fp8.
__device__ __forceinline__ void aggnorm_body(__half* rows, int s, int cnt, int e,
    const uint2* __restrict__ h8, const int* __restrict__ rowptr,
    const int* __restrict__ csr_src, const float* __restrict__ dinv,
    const float* __restrict__ bias, const float* __restrict__ gw,
    const float* __restrict__ gb, const float* __restrict__ ga,
    const float* __restrict__ W, unsigned char* __restrict__ out,
    float* red, float* red2, float* sam, float* ssc, float* srow) {
    int tid = threadIdx.x, lane = tid & 63, wid = tid >> 6;
    int f8 = lane & 7, e8 = lane >> 3;
    int passes = (cnt + 15) >> 4;  // 4 waves x 4 nodes per pass
    for (int p = 0; p < passes; ++p) {
        int n0 = __builtin_amdgcn_readfirstlane(s + p * 16 + wid * 4);
        if (n0 < e) {
            float r[8];
            int node = agg4_core(h8, rowptr, csr_src, dinv, bias, n0, e, lane, f8, e8, r);
            if (node >= 0) {
                HU o;
                o.h[0] = __floats2half2_rn(r[0], r[1]);
                o.h[1] = __floats2half2_rn(r[2], r[3]);
                o.h[2] = __floats2half2_rn(r[4], r[5]);
                o.h[3] = __floats2half2_rn(r[6], r[7]);
                ((uint4*)rows)[(size_t)(node - s) * 8 + f8] = o.u;
            }
        }
    }
    __syncthreads();
    float cntf = (float)(cnt > 1 ? cnt : 1);
    float sum = 0.f, sq = 0.f;
    for (int i = wid; i < cnt; i += 4) {
        float v = __half2float(rows[(size_t)i * 64 + lane]);
        sum += v;
        sq = fmaf(v, v, sq);
    }
    red[tid] = sum; red2[tid] = sq;
    __syncthreads();
    for (int st = 2; st > 0; st >>= 1) {
        if (wid < st) { red[tid] += red[tid + st * 64]; red2[tid] += red2[tid + st * 64]; }
        __syncthreads();
    }
    if (tid < 64) {
        float m = red[tid] / cntf, q = red2[tid] / cntf;
        float am = ga[tid] * m;
        sam[tid] = am;
        ssc[tid] = gw[tid] * rsqrtf(q - 2.f * am * m + am * am + GN_EPS);
    }
    __syncthreads();
    float wcol[64];
#pragma unroll
    for (int k = 0; k < 64; k++) wcol[k] = W[k * 64 + lane];
    float am = sam[lane], sc = ssc[lane], bb = gb[lane];
    for (int i = wid; i < cnt; i += 4) {
        float nv = (__half2float(rows[(size_t)i * 64 + lane]) - am) * sc + bb;
        srow[wid * 64 + lane] = nv;
        float acc = 0.f;
#pragma unroll
        for (int k = 0; k < 64; k++) acc = fmaf(srow[wid * 64 + k], wcol[k], acc);
        out[(size_t)(s + i) * 64 + lane] = f2fp8(acc * dinv[s + i]);
    }
}

__global__ __launch_bounds__(256, 4) void fused_aggnorm_k(
    const unsigned char* __restrict__ hs_in, const int* __restrict__ gstart,
    const int* __restrict__ rowptr, const int* __restrict__ csr_src,
    const float* __restrict__ dinv, const float* __restrict__ bias,
    const float* __restrict__ gw, const float* __restrict__ gb,
    const float* __restrict__ ga, const float* __restrict__ W,
    unsigned char* __restrict__ out, __half* __restrict__ spill) {
    __shared__ alignas(16) __half sA[CAP * 64];  // 20 KB
    __shared__ float red[256], red2[256];
    __shared__ float sam[64], ssc[64];
    __shared__ float srow[4 * 64];
    int g = blockIdx.x;
    int s = gstart[g], e = gstart[g + 1], cnt = e - s;
    const uint2* h8 = (const uint2*)hs_in;
    if (cnt <= CAP)
        aggnorm_body(sA, s, cnt, e, h8, rowptr, csr_src, dinv, bias,
                     gw, gb, ga, W, out, red, red2, sam, ssc, srow);
    else
        aggnorm_body(spill + (size_t)s * 64, s, cnt, e, h8, rowptr, csr_src, dinv, bias,
                     gw, gb, ga, W, out, red, red2, sam, ssc, srow);
}

// ---- fused last aggregate + mean-pool + MLP head + softmax (fp8 input) ----
__global__ __launch_bounds__(256, 4) void fused_aggpool_k(
    const unsigned char* __restrict__ hs_in, const int* __restrict__ gstart,
    const int* __restrict__ rowptr, const int* __restrict__ csr_src,
    const float* __restrict__ dinv, const float* __restrict__ bias,
    const float* __restrict__ Wd, const float* __restrict__ bd,
    const float* __restrict__ Wo, const float* __restrict__ bo,
    float* __restrict__ out) {
    __shared__ float wpart[4 * 64];
    __shared__ float sp[64];
    __shared__ float sh[64];
    __shared__ float sl[2];
    int tid = threadIdx.x, lane = tid & 63, wid = tid >> 6;
    int f8 = lane & 7, e8 = lane >> 3;
    int g = blockIdx.x;
    int s = gstart[g], e = gstart[g + 1], cnt = e - s;
    const uint2* h8 = (const uint2*)hs_in;
    float pacc[8];
#pragma unroll
    for (int j = 0; j < 8; j++) pacc[j] = 0.f;
    int passes = (cnt + 15) >> 4;
    for (int p = 0; p < passes; ++p) {
        int n0 = __builtin_amdgcn_readfirstlane(s + p * 16 + wid * 4);
        if (n0 < e) {
            float r[8];
            int node = agg4_core(h8, rowptr, csr_src, dinv, bias, n0, e, lane, f8, e8, r);
            if (node >= 0) {
#pragma unroll
                for (int j = 0; j < 8; j++) pacc[j] += r[j];
            }
        }
    }
#pragma unroll
    for (int j = 0; j < 8; j++) {
        float v = pacc[j];
        v += __shfl_xor(v, 8, 64);
        v += __shfl_xor(v, 16, 64);
        v += __shfl_xor(v, 32, 64);
        pacc[j] = v;
    }
    if (lane < 8) {
#pragma unroll
        for (int j = 0; j < 8; j++) wpart[wid * 64 + lane * 8 + j] = pacc[j];
    }
    __syncthreads();
    float cntf = (float)(cnt > 1 ? cnt : 1);
    if (tid < 64)
        sp[tid] = (wpart[tid] + wpart[64 + tid] + wpart[128 + tid] + wpart[192 + tid]) / cntf;
    __syncthreads();
    if (tid < 64) {
        float acc = bd[tid];
        for (int k = 0; k < 64; k++) acc = fmaf(sp[k], Wd[k * 64 + tid], acc);
        sh[tid] = acc > 0.f ? acc : 0.f;
    }
    __syncthreads();
    if (tid < 2) {
        float l = bo[tid];
        for (int k = 0; k < 64; k++) l = fmaf(sh[k], Wo[k * 2 + tid], l);
        sl[tid] = l;
    }
    __syncthreads();
    if (tid < 2) {
        float m = fmaxf(sl[0], sl[1]);
        float e0 = expf(sl[0] - m), e1 = expf(sl[1] - m);
        out[g * 2 + tid] = (tid == 0 ? e0 : e1) / (e0 + e1);
    }
}

// ---- layer-1 gather (16-dim), lane-per-node (R7, proven): pair owns a node;
// serial edges from LDS-staged idx; zero shuffles; y16 table L2-resident.
__device__ __forceinline__ void l1_gather(__half* rows16, int s, int cnt,
    const uint4* __restrict__ yv, const int* __restrict__ rowptr,
    const int* __restrict__ csr_src, const int* eidx, bool lds_e, int eb, int tid) {
    int f2 = tid & 1;
    uint4* r16 = (uint4*)rows16;
    for (int ln = (tid >> 1); ln < cnt; ln += 128) {
        int rb = rowptr[s + ln];
        int d = rowptr[s + ln + 1] - rb;
        HU acc;
        acc.u = yv[(size_t)(s + ln) * 2 + f2];   // self row half
        if (lds_e) {
            int o = rb - eb;
            int t = 0;
            for (; t + 4 <= d; t += 4) {
                int u0 = eidx[o + t], u1 = eidx[o + t + 1];
                int u2 = eidx[o + t + 2], u3 = eidx[o + t + 3];
                uint4 g0 = yv[(size_t)u0 * 2 + f2];
                uint4 g1 = yv[(size_t)u1 * 2 + f2];
                uint4 g2 = yv[(size_t)u2 * 2 + f2];
                uint4 g3 = yv[(size_t)u3 * 2 + f2];
                pkacc(acc.h, g0);
                pkacc(acc.h, g1);
                pkacc(acc.h, g2);
                pkacc(acc.h, g3);
            }
            for (; t < d; ++t) {
                int u = eidx[o + t];
                pkacc(acc.h, yv[(size_t)u * 2 + f2]);
            }
        } else {
            for (int t = 0; t < d; ++t) {
                int u = csr_src[rb + t];
                pkacc(acc.h, yv[(size_t)u * 2 + f2]);
            }
        }
        r16[(size_t)ln * 2 + f2] = acc.u;
    }
}

// ---- fused layer 1: gather16 -> @W1+b1+relu (+stats) -> GraphNorm1 -> @W2*dinv,
// output written as fp8 (layer-2 gather input).
__device__ __forceinline__ void l1_body(__half* rows64, __half* rows16,
    int s, int cnt,
    const uint4* __restrict__ yv, const int* __restrict__ rowptr,
    const int* __restrict__ csr_src, const int* eidx, bool lds_e, int eb,
    const float* __restrict__ dinv,
    const float* __restrict__ W1, const float* __restrict__ b1,
    const float* __restrict__ gw, const float* __restrict__ gb,
    const float* __restrict__ ga, const float* __restrict__ W2,
    unsigned char* __restrict__ out,
    float* red, float* red2, float* sam, float* ssc, float* srow) {
    int tid = threadIdx.x, lane = tid & 63, wid = tid >> 6;
    l1_gather(rows16, s, cnt, yv, rowptr, csr_src, eidx, lds_e, eb, tid);
    __syncthreads();
    // phase 2: h = relu(dot(raw16, W1col)*dinv + b1); stats over h
    float w1c[16];
#pragma unroll
    for (int k = 0; k < 16; ++k) w1c[k] = W1[k * 64 + lane];
    float bb1 = b1[lane];
    const uint4* r16v = (const uint4*)rows16;
    float cntf = (float)(cnt > 1 ? cnt : 1);
    float sum = 0.f, sq = 0.f;
    for (int i = wid; i < cnt; i += 4) {
        HU q0, q1;
        q0.u = r16v[(size_t)i * 2];
        q1.u = r16v[(size_t)i * 2 + 1];
        float dn = dinv[s + i];
        float dot = 0.f;
#pragma unroll
        for (int j = 0; j < 4; ++j) {
            float2 v = __half22float2(q0.h[j]);
            dot = fmaf(v.x, w1c[2 * j], dot);
            dot = fmaf(v.y, w1c[2 * j + 1], dot);
        }
#pragma unroll
        for (int j = 0; j < 4; ++j) {
            float2 v = __half22float2(q1.h[j]);
            dot = fmaf(v.x, w1c[8 + 2 * j], dot);
            dot = fmaf(v.y, w1c[8 + 2 * j + 1], dot);
        }
        float h = fmaf(dot, dn, bb1);
        h = h > 0.f ? h : 0.f;
        rows64[(size_t)i * 64 + lane] = __float2half(h);
        sum += h;
        sq = fmaf(h, h, sq);
    }
    red[tid] = sum; red2[tid] = sq;
    __syncthreads();
    for (int st = 2; st > 0; st >>= 1) {
        if (wid < st) { red[tid] += red[tid + st * 64]; red2[tid] += red2[tid + st * 64]; }
        __syncthreads();
    }
    if (tid < 64) {
        float m = red[tid] / cntf, q = red2[tid] / cntf;
        float am = ga[tid] * m;
        sam[tid] = am;
        ssc[tid] = gw[tid] * rsqrtf(q - 2.f * am * m + am * am + GN_EPS);
    }
    __syncthreads();
    // phase 3: norm + @W2, out = fp8((.)*dinv)
    float wcol[64];
#pragma unroll
    for (int k = 0; k < 64; k++) wcol[k] = W2[k * 64 + lane];
    float am = sam[lane], sc = ssc[lane], bbg = gb[lane];
    for (int i = wid; i < cnt; i += 4) {
        float nv = (__half2float(rows64[(size_t)i * 64 + lane]) - am) * sc + bbg;
        srow[wid * 64 + lane] = nv;
        float acc = 0.f;
#pragma unroll
        for (int k = 0; k < 64; k++) acc = fmaf(srow[wid * 64 + k], wcol[k], acc);
        out[(size_t)(s + i) * 64 + lane] = f2fp8(acc * dinv[s + i]);
    }
}

__global__ __launch_bounds__(256, 4) void fused_l1_k(
    const __half* __restrict__ y16, const int* __restrict__ gstart,
    const int* __restrict__ rowptr, const int* __restrict__ csr_src,
    const float* __restrict__ dinv, const float* __restrict__ W1,
    const float* __restrict__ b1, const float* __restrict__ gw,
    const float* __restrict__ gb, const float* __restrict__ ga,
    const float* __restrict__ W2, unsigned char* __restrict__ out,
    __half* __restrict__ spill64, __half* __restrict__ spill16) {
    __shared__ alignas(16) __half sR64[CAP * 64];  // 20 KB
    __shared__ alignas(16) __half sR16[CAP * 16];  // 5 KB
    __shared__ int arena[ECAP];                    // 8 KB (edge idx staging)
    __shared__ float red[256], red2[256];
    __shared__ float sam[64], ssc[64];
    __shared__ float srow[4 * 64];
    int tid = threadIdx.x;
    int g = blockIdx.x;
    int s = gstart[g], e = gstart[g + 1], cnt = e - s;
    int eb = rowptr[s], m = rowptr[e] - eb;
    const uint4* yv = (const uint4*)y16;
    bool lds_e = (m <= ECAP);
    if (lds_e) for (int i = tid; i < m; i += 256) arena[i] = csr_src[eb + i];
    __syncthreads();
    if (cnt <= CAP)
        l1_body(sR64, sR16, s, cnt, yv, rowptr, csr_src, arena, lds_e, eb, dinv,
                W1, b1, gw, gb, ga, W2, out, red, red2, sam, ssc, srow);
    else
        l1_body(spill64 + (size_t)s * 64, spill16 + (size_t)s * 16, s, cnt,
                yv, rowptr, csr_src, arena, lds_e, eb, dinv,
                W1, b1, gw, gb, ga, W2, out, red, red2, sam, ssc, srow);
}

// ---------------- layer0: GraphNorm(16) * dinv -> y16 [N][16] fp16 ----------------
__device__ __forceinline__ void l0_body(float* rows, int cnt, int s,
    const float* __restrict__ x, const float* __restrict__ gw,
    const float* __restrict__ gb, const float* __restrict__ ga,
    const float* __restrict__ dinv, __half* __restrict__ y16,
    float* red, float* red2, float* sstat, float* sscale, int tid) {
    int f = tid & 15, r = tid >> 4;
    float cntf = (float)(cnt > 1 ? cnt : 1);
    float sum = 0.f, sq = 0.f;
    for (int i = r; i < cnt; i += 32) {
        float v = x[(size_t)(s + i) * 16 + f];
        rows[i * 16 + f] = v;
        sum += v;
        sq = fmaf(v, v, sq);
    }
    red[tid] = sum; red2[tid] = sq;
    __syncthreads();
    for (int st = 16; st > 0; st >>= 1) {
        if (r < st) { red[tid] += red[tid + st * 16]; red2[tid] += red2[tid + st * 16]; }
        __syncthreads();
    }
    if (tid < 16) {
        float m = red[tid] / cntf, q = red2[tid] / cntf;
        float am = ga[tid] * m;
        sstat[tid] = am;
        sscale[tid] = gw[tid] * rsqrtf(q - 2.f * am * m + am * am + GN_EPS);
    }
    __syncthreads();
    float am = sstat[f], sc = sscale[f], bb = gb[f];
    for (int i = r; i < cnt; i += 32) {
        float nv = (rows[i * 16 + f] - am) * sc + bb;
        y16[(size_t)(s + i) * 16 + f] = __float2half(nv * dinv[s + i]);
    }
}

__global__ __launch_bounds__(512) void layer0_k(const float* __restrict__ x,
    const int* __restrict__ gstart, const float* __restrict__ gw,
    const float* __restrict__ gb, const float* __restrict__ ga,
    const float* __restrict__ dinv, __half* __restrict__ y16,
    float* __restrict__ spill16f) {
    __shared__ float sRows[CAP * 16];
    __shared__ float red[512], red2[512];
    __shared__ float sstat[16], sscale[16];
    int tid = threadIdx.x;
    int g = blockIdx.x;
    int s = gstart[g], e = gstart[g + 1], cnt = e - s;
    if (cnt <= CAP)
        l0_body(sRows, cnt, s, x, gw, gb, ga, dinv, y16, red, red2, sstat, sscale, tid);
    else
        l0_body(spill16f + (size_t)s * 16, cnt, s, x, gw, gb, ga, dinv, y16, red, red2, sstat, sscale, tid);
}

extern "C" void kernel_launch(void* const* d_in, const int* in_sizes, int n_in,
                              void* d_out, int out_size, void* d_ws, size_t ws_size,
                              hipStream_t stream) {
    const float* x    = (const float*)d_in[0];
    const int* ei     = (const int*)d_in[1];
    const int* batch  = (const int*)d_in[2];
    const float* gn0w = (const float*)d_in[3];
    const float* gn0b = (const float*)d_in[4];
    const float* gn0a = (const float*)d_in[5];
    const float* W1   = (const float*)d_in[6];
    const float* b1   = (const float*)d_in[7];
    const float* gn1w = (const float*)d_in[8];
    const float* gn1b = (const float*)d_in[9];
    const float* gn1a = (const float*)d_in[10];
    const float* W2   = (const float*)d_in[11];
    const float* b2   = (const float*)d_in[12];
    const float* gn2w = (const float*)d_in[13];
    const float* gn2b = (const float*)d_in[14];
    const float* gn2a = (const float*)d_in[15];
    const float* W3   = (const float*)d_in[16];
    const float* b3   = (const float*)d_in[17];
    const float* Wd   = (const float*)d_in[18];
    const float* bd   = (const float*)d_in[19];
    const float* Wo   = (const float*)d_in[20];
    const float* bo   = (const float*)d_in[21];

    char* p = (char*)d_ws;
    auto alloc = [&](size_t bytes) -> void* {
        void* r = (void*)p;
        p += (bytes + 255) & ~(size_t)255;
        return r;
    };
    unsigned char* A = (unsigned char*)alloc((size_t)NB_NODES * 64);  // fp8 activations
    unsigned char* B = (unsigned char*)alloc((size_t)NB_NODES * 64);  // fp8 activations
    __half* y16      = (__half*)alloc((size_t)NB_NODES * 16 * 2);
    int* rowptr      = (int*)alloc((size_t)(NB_NODES + 1) * 4);
    unsigned* ebuf   = (unsigned*)alloc((size_t)NB_EDGES * 4);
    int* csr_src     = (int*)alloc((size_t)NB_EDGES * 4);
    int* hist        = (int*)alloc((size_t)NBLK1 * NBUCK * 4);
    int* total       = (int*)alloc((size_t)NBUCK * 4);
    float* dinv      = (float*)alloc((size_t)NB_NODES * 4);
    int* gstart      = (int*)alloc((size_t)(NB_GRAPHS + 1) * 4);
    float* spill16f  = (float*)alloc((size_t)NB_NODES * 16 * 4);
    __half* spillH   = (__half*)alloc((size_t)NB_NODES * 64 * 2);
    __half* spillQ   = (__half*)alloc((size_t)NB_NODES * 16 * 2);

    k1_hist<<<NBLK1, 256, 0, stream>>>(ei + NB_EDGES, hist, batch, gstart);
    k2a_scan<<<NBUCK, 512, 0, stream>>>(hist, total);
    k3_scatter<<<NBLK1, 256, 0, stream>>>(ei, hist, total, ebuf);
    k4_fine<<<NBUCK, 256, 0, stream>>>(ebuf, total, csr_src, rowptr, dinv);

    layer0_k<<<NB_GRAPHS, 512, 0, stream>>>(x, gstart, gn0w, gn0b, gn0a, dinv, y16, spill16f);
    fused_l1_k<<<NB_GRAPHS, 256, 0, stream>>>(y16, gstart, rowptr, csr_src, dinv,
                                              W1, b1, gn1w, gn1b, gn1a, W2, A, spillH, spillQ);
    fused_aggnorm_k<<<NB_GRAPHS, 256, 0, stream>>>(A, gstart, rowptr, csr_src, dinv,
                                                   b2, gn2w, gn2b, gn2a, W3, B, spillH);
    fused_aggpool_k<<<NB_GRAPHS, 256, 0, stream>>>(B, gstart, rowptr, csr_src, dinv,
                                                   b3, Wd, bd, Wo, bo, (float*)d_out);
}

// Round 12
// 276.893 us; speedup vs baseline: 2.3920x; 1.0172x over previous
//
#include <hip/hip_runtime.h>
#include <hip/hip_fp16.h>
#include <math.h>

#define NB_NODES 100000
#define NB_EDGES 1600000
#define NB_GRAPHS 1000
#define CAP 160        // max nodes/graph in LDS (true max ~135; spill path beyond)
#define ECAP 2048      // LDS edge cap per graph (mean 1600; global fallback beyond)
#define NBLK1 400      // coarse pass blocks
#define CHUNK 4000     // edges per coarse block (NBLK1*CHUNK == NB_EDGES)
#define NBUCK 391      // ceil(NB_NODES/256) coarse buckets (dst >> 8)
#define BCAP 4608      // max edges per bucket (mean 4096, sigma 64, +8 sigma)
constexpr float GN_EPS = 1e-5f;

// ---- K1: per-block LDS histogram over coarse buckets + gstart (blocks 0-3) ----
__global__ __launch_bounds__(256) void k1_hist(const int* __restrict__ dst,
    int* __restrict__ hist, const int* __restrict__ batch, int* __restrict__ gstart) {
    __shared__ int h[NBUCK];
    int tid = threadIdx.x;
    for (int i = tid; i < NBUCK; i += 256) h[i] = 0;
    if (blockIdx.x < 4) {
        int g = blockIdx.x * 256 + tid;
        if (g <= NB_GRAPHS) {
            int lo = 0, hi = NB_NODES;
            while (lo < hi) {
                int mid = (lo + hi) >> 1;
                if (batch[mid] < g) lo = mid + 1; else hi = mid;
            }
            gstart[g] = lo;
        }
    }
    __syncthreads();
    int base = blockIdx.x * CHUNK;
    for (int i = tid; i < CHUNK; i += 256) atomicAdd(&h[dst[base + i] >> 8], 1);
    __syncthreads();
    for (int i = tid; i < NBUCK; i += 256) hist[blockIdx.x * NBUCK + i] = h[i];
}

// ---- K2: per bucket, exclusive scan across the 400 blocks; emit totals ----
__global__ __launch_bounds__(512) void k2a_scan(int* __restrict__ hist,
                                                int* __restrict__ total) {
    __shared__ int s[512];
    int b = blockIdx.x;  // bucket
    int tid = threadIdx.x;
    int v = (tid < NBLK1) ? hist[tid * NBUCK + b] : 0;
    s[tid] = v;
    __syncthreads();
    for (int o = 1; o < 512; o <<= 1) {
        int t = (tid >= o) ? s[tid - o] : 0;
        __syncthreads();
        s[tid] += t;
        __syncthreads();
    }
    if (tid < NBLK1) hist[tid * NBUCK + b] = s[tid] - v;  // exclusive prefix in place
    if (tid == 511) total[b] = s[511];
}

// ---- K3: scatter into bucket-contiguous runs; base recomputed in-LDS from total ----
__global__ __launch_bounds__(256) void k3_scatter(const int* __restrict__ ei,
    const int* __restrict__ hist, const int* __restrict__ total,
    unsigned int* __restrict__ ebuf) {
    __shared__ int cur[NBUCK];
    __shared__ int sc[256];
    int tid = threadIdx.x;
    int e0 = 2 * tid, e1 = 2 * tid + 1;
    int v0 = (e0 < NBUCK) ? total[e0] : 0;
    int v1 = (e1 < NBUCK) ? total[e1] : 0;
    int own = v0 + v1;
    sc[tid] = own;
    __syncthreads();
    for (int o = 1; o < 256; o <<= 1) {
        int t = (tid >= o) ? sc[tid - o] : 0;
        __syncthreads();
        sc[tid] += t;
        __syncthreads();
    }
    int pre = sc[tid] - own;
    if (e0 < NBUCK) cur[e0] = pre + hist[blockIdx.x * NBUCK + e0];
    if (e1 < NBUCK) cur[e1] = pre + v0 + hist[blockIdx.x * NBUCK + e1];
    __syncthreads();
    int eb = blockIdx.x * CHUNK;
    for (int i = tid; i < CHUNK; i += 256) {
        int e = eb + i;
        int sidx = ei[e];
        int d = ei[NB_EDGES + e];
        int pos = atomicAdd(&cur[d >> 8], 1);
        ebuf[pos] = (unsigned int)sidx | ((unsigned int)(d & 255) << 24);
    }
}

// ---- K4: per-bucket fine CSR in LDS; base recomputed in-LDS from total ----
__global__ __launch_bounds__(256) void k4_fine(const unsigned int* __restrict__ ebuf,
    const int* __restrict__ total, int* __restrict__ csr_src, int* __restrict__ rowptr,
    float* __restrict__ dinv) {
    __shared__ int arena[2 * BCAP + 768];
    unsigned int* epk = (unsigned int*)arena;
    int* outb  = arena + BCAP;
    int* cnt   = arena + 2 * BCAP;          // 256
    int* sbuf  = arena + 2 * BCAP + 256;    // 256
    int* cur2  = arena + 2 * BCAP + 512;    // 256
    int* bases = arena + 2 * BCAP;          // 392 ints, phase0 only (overlaps cnt/sbuf)
    int b = blockIdx.x;
    int tid = threadIdx.x;
    int e0 = 2 * tid, e1 = 2 * tid + 1;
    int v0 = (e0 < NBUCK) ? total[e0] : 0;
    int v1 = (e1 < NBUCK) ? total[e1] : 0;
    int own = v0 + v1;
    cur2[tid] = own;
    __syncthreads();
    for (int o = 1; o < 256; o <<= 1) {
        int t = (tid >= o) ? cur2[tid - o] : 0;
        __syncthreads();
        cur2[tid] += t;
        __syncthreads();
    }
    int pre = cur2[tid] - own;
    if (e0 < NBUCK) bases[e0] = pre;
    if (e1 < NBUCK) bases[e1] = pre + v0;
    if (tid == 0) bases[NBUCK] = NB_EDGES;
    __syncthreads();
    int eb = bases[b], ee = bases[b + 1];
    __syncthreads();  // done with bases; cnt/sbuf reusable
    int m = ee - eb;
    if (m > BCAP) m = BCAP;  // memory-safety clamp (never expected)
    for (int i = tid; i < m; i += 256) epk[i] = ebuf[eb + i];
    cnt[tid] = 0;
    __syncthreads();
    for (int i = tid; i < m; i += 256) atomicAdd(&cnt[epk[i] >> 24], 1);
    __syncthreads();
    int c = cnt[tid];
    sbuf[tid] = c;
    __syncthreads();
    for (int o = 1; o < 256; o <<= 1) {
        int t = (tid >= o) ? sbuf[tid - o] : 0;
        __syncthreads();
        sbuf[tid] += t;
        __syncthreads();
    }
    int off = sbuf[tid] - c;  // exclusive scan
    cur2[tid] = off;
    __syncthreads();
    for (int i = tid; i < m; i += 256) {
        unsigned int p = epk[i];
        int r = atomicAdd(&cur2[p >> 24], 1);
        outb[r] = (int)(p & 0x00FFFFFFu);
    }
    __syncthreads();
    for (int i = tid; i < m; i += 256) csr_src[eb + i] = outb[i];
    int node = b * 256 + tid;
    if (node < NB_NODES) {
        rowptr[node] = eb + off;
        dinv[node] = rsqrtf((float)(c + 1));
    }
    if (b == 0 && tid == 0) rowptr[NB_NODES] = NB_EDGES;
}

// ---------------- fp16 helpers ----------------
union HU {
    uint4 u;
    __half2 h[4];
};

__device__ __forceinline__ void pkacc(__half2* a, uint4 v) {
    HU x; x.u = v;
    a[0] = __hadd2(a[0], x.h[0]);
    a[1] = __hadd2(a[1], x.h[1]);
    a[2] = __hadd2(a[2], x.h[2]);
    a[3] = __hadd2(a[3], x.h[3]);
}

__device__ __forceinline__ __half2 shxor_h2(__half2 v, int m) {
    union { __half2 h; int i; } u;
    u.h = v;
    u.i = __shfl_xor(u.i, m, 64);
    return u.h;
}

// --- 64-dim aggregate core (layers 2,3): 4 nodes/wave, R4-proven structure.
// SESSION VERDICT (R1-R11): this gather's ~58-60us is invariant to occupancy
// (R3), per-wave MLP depth (R4), byte volume / L2 residency / transaction
// count (R11 fp8: FETCH halved, dur unchanged). The floor is the VMEM
// address-processing path, not bytes, latency hiding, or VALU. fp16 kept:
// fp8's cvt overhead >= its memory savings (R11 net -1.3%).
__device__ __forceinline__ int agg4_core(const uint4* __restrict__ hsv,
    const int* __restrict__ rowptr, const int* __restrict__ csr_src,
    const float* __restrict__ dinv, const float* __restrict__ bias,
    int n0, int e, int lane, int f8, int e8, float r[8]) {
    int i2 = n0 + 2 < e ? n0 + 2 : e;
    int i3 = n0 + 3 < e ? n0 + 3 : e;
    int i4 = n0 + 4 < e ? n0 + 4 : e;
    int r0 = rowptr[n0], r1 = rowptr[n0 + 1], r2 = rowptr[i2];
    int r3 = rowptr[i3], r4 = rowptr[i4];
    int d0 = r1 - r0, d1 = r2 - r1, d2 = r3 - r2, d3 = r4 - r3;
    const uint4 Z = {0u, 0u, 0u, 0u};
    int idx0 = (lane < d0) ? csr_src[r0 + lane] : -1;
    int idx1 = (lane < d1) ? csr_src[r1 + lane] : -1;
    int idx2 = (lane < d2) ? csr_src[r2 + lane] : -1;
    int idx3 = (lane < d3) ? csr_src[r3 + lane] : -1;
    uint4 self = Z;
    if (e8 < 4 && n0 + e8 < e) self = hsv[(size_t)(n0 + e8) * 8 + f8];
    uint4 gA[8];
#pragma unroll
    for (int b = 0; b < 4; b++) {
        int u = __shfl(idx0, b * 8 + e8, 64);
        gA[b] = Z;
        if (u >= 0) gA[b] = hsv[(size_t)u * 8 + f8];
        int v = __shfl(idx1, b * 8 + e8, 64);
        gA[4 + b] = Z;
        if (v >= 0) gA[4 + b] = hsv[(size_t)v * 8 + f8];
    }
    uint4 gB[8];
#pragma unroll
    for (int b = 0; b < 4; b++) {
        int u = __shfl(idx2, b * 8 + e8, 64);
        gB[b] = Z;
        if (u >= 0) gB[b] = hsv[(size_t)u * 8 + f8];
        int v = __shfl(idx3, b * 8 + e8, 64);
        gB[4 + b] = Z;
        if (v >= 0) gB[4 + b] = hsv[(size_t)v * 8 + f8];
    }
    __half2 acc0[4], acc1[4], acc2[4], acc3[4];
    __half2 z2{__half(0.f), __half(0.f)};
    acc0[0] = acc0[1] = acc0[2] = acc0[3] = z2;
    acc1[0] = acc1[1] = acc1[2] = acc1[3] = z2;
    acc2[0] = acc2[1] = acc2[2] = acc2[3] = z2;
    acc3[0] = acc3[1] = acc3[2] = acc3[3] = z2;
    if (e8 == 0) pkacc(acc0, self);
    if (e8 == 1) pkacc(acc1, self);
    if (e8 == 2) pkacc(acc2, self);
    if (e8 == 3) pkacc(acc3, self);
#pragma unroll
    for (int b = 0; b < 4; b++) { pkacc(acc0, gA[b]); pkacc(acc1, gA[4 + b]); }
#pragma unroll
    for (int b = 0; b < 4; b++) { pkacc(acc2, gB[b]); pkacc(acc3, gB[4 + b]); }
    int tb0 = (d0 + 7) >> 3, tb1 = (d1 + 7) >> 3;
    int tb2 = (d2 + 7) >> 3, tb3 = (d3 + 7) >> 3;
    for (int b = 4; b < tb0 && b < 8; b++) {
        int u = __shfl(idx0, b * 8 + e8, 64);
        if (u >= 0) pkacc(acc0, hsv[(size_t)u * 8 + f8]);
    }
    for (int b = 4; b < tb1 && b < 8; b++) {
        int u = __shfl(idx1, b * 8 + e8, 64);
        if (u >= 0) pkacc(acc1, hsv[(size_t)u * 8 + f8]);
    }
    for (int b = 4; b < tb2 && b < 8; b++) {
        int u = __shfl(idx2, b * 8 + e8, 64);
        if (u >= 0) pkacc(acc2, hsv[(size_t)u * 8 + f8]);
    }
    for (int b = 4; b < tb3 && b < 8; b++) {
        int u = __shfl(idx3, b * 8 + e8, 64);
        if (u >= 0) pkacc(acc3, hsv[(size_t)u * 8 + f8]);
    }
    for (int b = 8; b < tb0; b++) {
        int j = r0 + b * 8 + e8;
        if (j < r1) pkacc(acc0, hsv[(size_t)csr_src[j] * 8 + f8]);
    }
    for (int b = 8; b < tb1; b++) {
        int j = r1 + b * 8 + e8;
        if (j < r2) pkacc(acc1, hsv[(size_t)csr_src[j] * 8 + f8]);
    }
    for (int b = 8; b < tb2; b++) {
        int j = r2 + b * 8 + e8;
        if (j < r3) pkacc(acc2, hsv[(size_t)csr_src[j] * 8 + f8]);
    }
    for (int b = 8; b < tb3; b++) {
        int j = r3 + b * 8 + e8;
        if (j < r4) pkacc(acc3, hsv[(size_t)csr_src[j] * 8 + f8]);
    }
#pragma unroll
    for (int c = 0; c < 4; c++) {
        __half2 t0 = acc0[c];
        t0 = __hadd2(t0, shxor_h2(t0, 8));
        t0 = __hadd2(t0, shxor_h2(t0, 16));
        t0 = __hadd2(t0, shxor_h2(t0, 32));
        acc0[c] = t0;
        __half2 t1 = acc1[c];
        t1 = __hadd2(t1, shxor_h2(t1, 8));
        t1 = __hadd2(t1, shxor_h2(t1, 16));
        t1 = __hadd2(t1, shxor_h2(t1, 32));
        acc1[c] = t1;
        __half2 t2 = acc2[c];
        t2 = __hadd2(t2, shxor_h2(t2, 8));
        t2 = __hadd2(t2, shxor_h2(t2, 16));
        t2 = __hadd2(t2, shxor_h2(t2, 32));
        acc2[c] = t2;
        __half2 t3 = acc3[c];
        t3 = __hadd2(t3, shxor_h2(t3, 8));
        t3 = __hadd2(t3, shxor_h2(t3, 16));
        t3 = __hadd2(t3, shxor_h2(t3, 32));
        acc3[c] = t3;
    }
    if (e8 >= 4) return -1;
    int node = n0 + e8;
    if (node >= e) return -1;
    const __half2* acc = (e8 == 0) ? acc0 : (e8 == 1) ? acc1 : (e8 == 2) ? acc2 : acc3;
    float dn = dinv[node];
    const float4* b4 = (const float4*)bias;
    float4 blo = b4[f8 * 2], bhi = b4[f8 * 2 + 1];
    float2 f0 = __half22float2(acc[0]);
    float2 f1 = __half22float2(acc[1]);
    float2 f2 = __half22float2(acc[2]);
    float2 f3 = __half22float2(acc[3]);
    r[0] = fmaf(f0.x, dn, blo.x); r[1] = fmaf(f0.y, dn, blo.y);
    r[2] = fmaf(f1.x, dn, blo.z); r[3] = fmaf(f1.y, dn, blo.w);
    r[4] = fmaf(f2.x, dn, bhi.x); r[5] = fmaf(f2.y, dn, bhi.y);
    r[6] = fmaf(f3.x, dn, bhi.z); r[7] = fmaf(f3.y, dn, bhi.w);
#pragma unroll
    for (int c = 0; c < 8; c++) r[c] = r[c] > 0.f ? r[c] : 0.f;
    return node;
}

// ---- fused aggregate + GraphNorm + 64x64 linear + dinv prescale (layer 2) ----
__device__ __forceinline__ void aggnorm_body(__half* rows, int s, int cnt, int e,
    const uint4* __restrict__ hsv, const int* __restrict__ rowptr,
    const int* __restrict__ csr_src, const float* __restrict__ dinv,
    const float* __restrict__ bias, const float* __restrict__ gw,
    const float* __restrict__ gb, const float* __restrict__ ga,
    const float* __restrict__ W, __half* __restrict__ out,
    float* red, float* red2, float* sam, float* ssc, float* srow) {
    int tid = threadIdx.x, lane = tid & 63, wid = tid >> 6;
    int f8 = lane & 7, e8 = lane >> 3;
    int passes = (cnt + 15) >> 4;  // 4 waves x 4 nodes per pass
    for (int p = 0; p < passes; ++p) {
        int n0 = __builtin_amdgcn_readfirstlane(s + p * 16 + wid * 4);
        if (n0 < e) {
            float r[8];
            int node = agg4_core(hsv, rowptr, csr_src, dinv, bias, n0, e, lane, f8, e8, r);
            if (node >= 0) {
                HU o;
                o.h[0] = __floats2half2_rn(r[0], r[1]);
                o.h[1] = __floats2half2_rn(r[2], r[3]);
                o.h[2] = __floats2half2_rn(r[4], r[5]);
                o.h[3] = __floats2half2_rn(r[6], r[7]);
                ((uint4*)rows)[(size_t)(node - s) * 8 + f8] = o.u;
            }
        }
    }
    __syncthreads();
    float cntf = (float)(cnt > 1 ? cnt : 1);
    float sum = 0.f, sq = 0.f;
    for (int i = wid; i < cnt; i += 4) {
        float v = __half2float(rows[(size_t)i * 64 + lane]);
        sum += v;
        sq = fmaf(v, v, sq);
    }
    red[tid] = sum; red2[tid] = sq;
    __syncthreads();
    for (int st = 2; st > 0; st >>= 1) {
        if (wid < st) { red[tid] += red[tid + st * 64]; red2[tid] += red2[tid + st * 64]; }
        __syncthreads();
    }
    if (tid < 64) {
        float m = red[tid] / cntf, q = red2[tid] / cntf;
        float am = ga[tid] * m;
        sam[tid] = am;
        ssc[tid] = gw[tid] * rsqrtf(q - 2.f * am * m + am * am + GN_EPS);
    }
    __syncthreads();
    float wcol[64];
#pragma unroll
    for (int k = 0; k < 64; k++) wcol[k] = W[k * 64 + lane];
    float am = sam[lane], sc = ssc[lane], bb = gb[lane];
    for (int i = wid; i < cnt; i += 4) {
        float nv = (__half2float(rows[(size_t)i * 64 + lane]) - am) * sc + bb;
        srow[wid * 64 + lane] = nv;
        float acc = 0.f;
#pragma unroll
        for (int k = 0; k < 64; k++) acc = fmaf(srow[wid * 64 + k], wcol[k], acc);
        out[(size_t)(s + i) * 64 + lane] = __float2half(acc * dinv[s + i]);
    }
}

__global__ __launch_bounds__(256, 4) void fused_aggnorm_k(
    const __half* __restrict__ hs_in, const int* __restrict__ gstart,
    const int* __restrict__ rowptr, const int* __restrict__ csr_src,
    const float* __restrict__ dinv, const float* __restrict__ bias,
    const float* __restrict__ gw, const float* __restrict__ gb,
    const float* __restrict__ ga, const float* __restrict__ W,
    __half* __restrict__ out, __half* __restrict__ spill) {
    __shared__ alignas(16) __half sA[CAP * 64];  // 20 KB
    __shared__ float red[256], red2[256];
    __shared__ float sam[64], ssc[64];
    __shared__ float srow[4 * 64];
    int g = blockIdx.x;
    int s = gstart[g], e = gstart[g + 1], cnt = e - s;
    const uint4* hsv = (const uint4*)hs_in;
    if (cnt <= CAP)
        aggnorm_body(sA, s, cnt, e, hsv, rowptr, csr_src, dinv, bias,
                     gw, gb, ga, W, out, red, red2, sam, ssc, srow);
    else
        aggnorm_body(spill + (size_t)s * 64, s, cnt, e, hsv, rowptr, csr_src, dinv, bias,
                     gw, gb, ga, W, out, red, red2, sam, ssc, srow);
}

// ---- fused last aggregate + mean-pool + MLP head + softmax, per-graph block ----
__global__ __launch_bounds__(256, 4) void fused_aggpool_k(
    const __half* __restrict__ hs_in, const int* __restrict__ gstart,
    const int* __restrict__ rowptr, const int* __restrict__ csr_src,
    const float* __restrict__ dinv, const float* __restrict__ bias,
    const float* __restrict__ Wd, const float* __restrict__ bd,
    const float* __restrict__ Wo, const float* __restrict__ bo,
    float* __restrict__ out) {
    __shared__ float wpart[4 * 64];
    __shared__ float sp[64];
    __shared__ float sh[64];
    __shared__ float sl[2];
    int tid = threadIdx.x, lane = tid & 63, wid = tid >> 6;
    int f8 = lane & 7, e8 = lane >> 3;
    int g = blockIdx.x;
    int s = gstart[g], e = gstart[g + 1], cnt = e - s;
    const uint4* hsv = (const uint4*)hs_in;
    float pacc[8];
#pragma unroll
    for (int j = 0; j < 8; j++) pacc[j] = 0.f;
    int passes = (cnt + 15) >> 4;
    for (int p = 0; p < passes; ++p) {
        int n0 = __builtin_amdgcn_readfirstlane(s + p * 16 + wid * 4);
        if (n0 < e) {
            float r[8];
            int node = agg4_core(hsv, rowptr, csr_src, dinv, bias, n0, e, lane, f8, e8, r);
            if (node >= 0) {
#pragma unroll
                for (int j = 0; j < 8; j++) pacc[j] += r[j];
            }
        }
    }
#pragma unroll
    for (int j = 0; j < 8; j++) {
        float v = pacc[j];
        v += __shfl_xor(v, 8, 64);
        v += __shfl_xor(v, 16, 64);
        v += __shfl_xor(v, 32, 64);
        pacc[j] = v;
    }
    if (lane < 8) {
#pragma unroll
        for (int j = 0; j < 8; j++) wpart[wid * 64 + lane * 8 + j] = pacc[j];
    }
    __syncthreads();
    float cntf = (float)(cnt > 1 ? cnt : 1);
    if (tid < 64)
        sp[tid] = (wpart[tid] + wpart[64 + tid] + wpart[128 + tid] + wpart[192 + tid]) / cntf;
    __syncthreads();
    if (tid < 64) {
        float acc = bd[tid];
        for (int k = 0; k < 64; k++) acc = fmaf(sp[k], Wd[k * 64 + tid], acc);
        sh[tid] = acc > 0.f ? acc : 0.f;
    }
    __syncthreads();
    if (tid < 2) {
        float l = bo[tid];
        for (int k = 0; k < 64; k++) l = fmaf(sh[k], Wo[k * 2 + tid], l);
        sl[tid] = l;
    }
    __syncthreads();
    if (tid < 2) {
        float m = fmaxf(sl[0], sl[1]);
        float e0 = expf(sl[0] - m), e1 = expf(sl[1] - m);
        out[g * 2 + tid] = (tid == 0 ? e0 : e1) / (e0 + e1);
    }
}

// ---- layer-1 gather (16-dim), lane-per-node: pair owns a node; serial edges
// from LDS-staged idx; zero shuffles; y16 table (3.2MB) L2-resident.
__device__ __forceinline__ void l1_gather(__half* rows16, int s, int cnt,
    const uint4* __restrict__ yv, const int* __restrict__ rowptr,
    const int* __restrict__ csr_src, const int* eidx, bool lds_e, int eb, int tid) {
    int f2 = tid & 1;
    uint4* r16 = (uint4*)rows16;
    for (int ln = (tid >> 1); ln < cnt; ln += 128) {
        int rb = rowptr[s + ln];
        int d = rowptr[s + ln + 1] - rb;
        HU acc;
        acc.u = yv[(size_t)(s + ln) * 2 + f2];   // self row half
        if (lds_e) {
            int o = rb - eb;
            int t = 0;
            for (; t + 4 <= d; t += 4) {
                int u0 = eidx[o + t], u1 = eidx[o + t + 1];
                int u2 = eidx[o + t + 2], u3 = eidx[o + t + 3];
                uint4 g0 = yv[(size_t)u0 * 2 + f2];
                uint4 g1 = yv[(size_t)u1 * 2 + f2];
                uint4 g2 = yv[(size_t)u2 * 2 + f2];
                uint4 g3 = yv[(size_t)u3 * 2 + f2];
                pkacc(acc.h, g0);
                pkacc(acc.h, g1);
                pkacc(acc.h, g2);
                pkacc(acc.h, g3);
            }
            for (; t < d; ++t) {
                int u = eidx[o + t];
                pkacc(acc.h, yv[(size_t)u * 2 + f2]);
            }
        } else {
            for (int t = 0; t < d; ++t) {
                int u = csr_src[rb + t];
                pkacc(acc.h, yv[(size_t)u * 2 + f2]);
            }
        }
        r16[(size_t)ln * 2 + f2] = acc.u;
    }
}

// ---- fused layer 1: gather16 -> @W1+b1+relu (+stats) -> GraphNorm1 -> @W2*dinv ----
__device__ __forceinline__ void l1_body(__half* rows64, __half* rows16,
    int s, int cnt,
    const uint4* __restrict__ yv, const int* __restrict__ rowptr,
    const int* __restrict__ csr_src, const int* eidx, bool lds_e, int eb,
    const float* __restrict__ dinv,
    const float* __restrict__ W1, const float* __restrict__ b1,
    const float* __restrict__ gw, const float* __restrict__ gb,
    const float* __restrict__ ga, const float* __restrict__ W2,
    __half* __restrict__ out,
    float* red, float* red2, float* sam, float* ssc, float* srow) {
    int tid = threadIdx.x, lane = tid & 63, wid = tid >> 6;
    l1_gather(rows16, s, cnt, yv, rowptr, csr_src, eidx, lds_e, eb, tid);
    __syncthreads();
    // phase 2: h = relu(dot(raw16, W1col)*dinv + b1); stats over h
    float w1c[16];
#pragma unroll
    for (int k = 0; k < 16; ++k) w1c[k] = W1[k * 64 + lane];
    float bb1 = b1[lane];
    const uint4* r16v = (const uint4*)rows16;
    float cntf = (float)(cnt > 1 ? cnt : 1);
    float sum = 0.f, sq = 0.f;
    for (int i = wid; i < cnt; i += 4) {
        HU q0, q1;
        q0.u = r16v[(size_t)i * 2];
        q1.u = r16v[(size_t)i * 2 + 1];
        float dn = dinv[s + i];
        float dot = 0.f;
#pragma unroll
        for (int j = 0; j < 4; ++j) {
            float2 v = __half22float2(q0.h[j]);
            dot = fmaf(v.x, w1c[2 * j], dot);
            dot = fmaf(v.y, w1c[2 * j + 1], dot);
        }
#pragma unroll
        for (int j = 0; j < 4; ++j) {
            float2 v = __half22float2(q1.h[j]);
            dot = fmaf(v.x, w1c[8 + 2 * j], dot);
            dot = fmaf(v.y, w1c[8 + 2 * j + 1], dot);
        }
        float h = fmaf(dot, dn, bb1);
        h = h > 0.f ? h : 0.f;
        rows64[(size_t)i * 64 + lane] = __float2half(h);
        sum += h;
        sq = fmaf(h, h, sq);
    }
    red[tid] = sum; red2[tid] = sq;
    __syncthreads();
    for (int st = 2; st > 0; st >>= 1) {
        if (wid < st) { red[tid] += red[tid + st * 64]; red2[tid] += red2[tid + st * 64]; }
        __syncthreads();
    }
    if (tid < 64) {
        float m = red[tid] / cntf, q = red2[tid] / cntf;
        float am = ga[tid] * m;
        sam[tid] = am;
        ssc[tid] = gw[tid] * rsqrtf(q - 2.f * am * m + am * am + GN_EPS);
    }
    __syncthreads();
    // phase 3: norm + @W2, out*dinv
    float wcol[64];
#pragma unroll
    for (int k = 0; k < 64; k++) wcol[k] = W2[k * 64 + lane];
    float am = sam[lane], sc = ssc[lane], bbg = gb[lane];
    for (int i = wid; i < cnt; i += 4) {
        float nv = (__half2float(rows64[(size_t)i * 64 + lane]) - am) * sc + bbg;
        srow[wid * 64 + lane] = nv;
        float acc = 0.f;
#pragma unroll
        for (int k = 0; k < 64; k++) acc = fmaf(srow[wid * 64 + k], wcol[k], acc);
        out[(size_t)(s + i) * 64 + lane] = __float2half(acc * dinv[s + i]);
    }
}

__global__ __launch_bounds__(256, 4) void fused_l1_k(
    const __half* __restrict__ y16, const int* __restrict__ gstart,
    const int* __restrict__ rowptr, const int* __restrict__ csr_src,
    const float* __restrict__ dinv, const float* __restrict__ W1,
    const float* __restrict__ b1, const float* __restrict__ gw,
    const float* __restrict__ gb, const float* __restrict__ ga,
    const float* __restrict__ W2, __half* __restrict__ out,
    __half* __restrict__ spill64, __half* __restrict__ spill16) {
    __shared__ alignas(16) __half sR64[CAP * 64];  // 20 KB
    __shared__ alignas(16) __half sR16[CAP * 16];  // 5 KB
    __shared__ int arena[ECAP];                    // 8 KB (edge idx staging)
    __shared__ float red[256], red2[256];
    __shared__ float sam[64], ssc[64];
    __shared__ float srow[4 * 64];
    int tid = threadIdx.x;
    int g = blockIdx.x;
    int s = gstart[g], e = gstart[g + 1], cnt = e - s;
    int eb = rowptr[s], m = rowptr[e] - eb;
    const uint4* yv = (const uint4*)y16;
    bool lds_e = (m <= ECAP);
    if (lds_e) for (int i = tid; i < m; i += 256) arena[i] = csr_src[eb + i];
    __syncthreads();
    if (cnt <= CAP)
        l1_body(sR64, sR16, s, cnt, yv, rowptr, csr_src, arena, lds_e, eb, dinv,
                W1, b1, gw, gb, ga, W2, out, red, red2, sam, ssc, srow);
    else
        l1_body(spill64 + (size_t)s * 64, spill16 + (size_t)s * 16, s, cnt,
                yv, rowptr, csr_src, arena, lds_e, eb, dinv,
                W1, b1, gw, gb, ga, W2, out, red, red2, sam, ssc, srow);
}

// ---------------- layer0: GraphNorm(16) * dinv -> y16 [N][16] fp16 ----------------
__device__ __forceinline__ void l0_body(float* rows, int cnt, int s,
    const float* __restrict__ x, const float* __restrict__ gw,
    const float* __restrict__ gb, const float* __restrict__ ga,
    const float* __restrict__ dinv, __half* __restrict__ y16,
    float* red, float* red2, float* sstat, float* sscale, int tid) {
    int f = tid & 15, r = tid >> 4;
    float cntf = (float)(cnt > 1 ? cnt : 1);
    float sum = 0.f, sq = 0.f;
    for (int i = r; i < cnt; i += 32) {
        float v = x[(size_t)(s + i) * 16 + f];
        rows[i * 16 + f] = v;
        sum += v;
        sq = fmaf(v, v, sq);
    }
    red[tid] = sum; red2[tid] = sq;
    __syncthreads();
    for (int st = 16; st > 0; st >>= 1) {
        if (r < st) { red[tid] += red[tid + st * 16]; red2[tid] += red2[tid + st * 16]; }
        __syncthreads();
    }
    if (tid < 16) {
        float m = red[tid] / cntf, q = red2[tid] / cntf;
        float am = ga[tid] * m;
        sstat[tid] = am;
        sscale[tid] = gw[tid] * rsqrtf(q - 2.f * am * m + am * am + GN_EPS);
    }
    __syncthreads();
    float am = sstat[f], sc = sscale[f], bb = gb[f];
    for (int i = r; i < cnt; i += 32) {
        float nv = (rows[i * 16 + f] - am) * sc + bb;
        y16[(size_t)(s + i) * 16 + f] = __float2half(nv * dinv[s + i]);
    }
}

__global__ __launch_bounds__(512) void layer0_k(const float* __restrict__ x,
    const int* __restrict__ gstart, const float* __restrict__ gw,
    const float* __restrict__ gb, const float* __restrict__ ga,
    const float* __restrict__ dinv, __half* __restrict__ y16,
    float* __restrict__ spill16f) {
    __shared__ float sRows[CAP * 16];
    __shared__ float red[512], red2[512];
    __shared__ float sstat[16], sscale[16];
    int tid = threadIdx.x;
    int g = blockIdx.x;
    int s = gstart[g], e = gstart[g + 1], cnt = e - s;
    if (cnt <= CAP)
        l0_body(sRows, cnt, s, x, gw, gb, ga, dinv, y16, red, red2, sstat, sscale, tid);
    else
        l0_body(spill16f + (size_t)s * 16, cnt, s, x, gw, gb, ga, dinv, y16, red, red2, sstat, sscale, tid);
}

extern "C" void kernel_launch(void* const* d_in, const int* in_sizes, int n_in,
                              void* d_out, int out_size, void* d_ws, size_t ws_size,
                              hipStream_t stream) {
    const float* x    = (const float*)d_in[0];
    const int* ei     = (const int*)d_in[1];
    const int* batch  = (const int*)d_in[2];
    const float* gn0w = (const float*)d_in[3];
    const float* gn0b = (const float*)d_in[4];
    const float* gn0a = (const float*)d_in[5];
    const float* W1   = (const float*)d_in[6];
    const float* b1   = (const float*)d_in[7];
    const float* gn1w = (const float*)d_in[8];
    const float* gn1b = (const float*)d_in[9];
    const float* gn1a = (const float*)d_in[10];
    const float* W2   = (const float*)d_in[11];
    const float* b2   = (const float*)d_in[12];
    const float* gn2w = (const float*)d_in[13];
    const float* gn2b = (const float*)d_in[14];
    const float* gn2a = (const float*)d_in[15];
    const float* W3   = (const float*)d_in[16];
    const float* b3   = (const float*)d_in[17];
    const float* Wd   = (const float*)d_in[18];
    const float* bd   = (const float*)d_in[19];
    const float* Wo   = (const float*)d_in[20];
    const float* bo   = (const float*)d_in[21];

    char* p = (char*)d_ws;
    auto alloc = [&](size_t bytes) -> void* {
        void* r = (void*)p;
        p += (bytes + 255) & ~(size_t)255;
        return r;
    };
    __half* A        = (__half*)alloc((size_t)NB_NODES * 64 * 2);
    __half* B        = (__half*)alloc((size_t)NB_NODES * 64 * 2);
    __half* y16      = (__half*)alloc((size_t)NB_NODES * 16 * 2);
    int* rowptr      = (int*)alloc((size_t)(NB_NODES + 1) * 4);
    unsigned* ebuf   = (unsigned*)alloc((size_t)NB_EDGES * 4);
    int* csr_src     = (int*)alloc((size_t)NB_EDGES * 4);
    int* hist        = (int*)alloc((size_t)NBLK1 * NBUCK * 4);
    int* total       = (int*)alloc((size_t)NBUCK * 4);
    float* dinv      = (float*)alloc((size_t)NB_NODES * 4);
    int* gstart      = (int*)alloc((size_t)(NB_GRAPHS + 1) * 4);
    float* spill16f  = (float*)alloc((size_t)NB_NODES * 16 * 4);
    __half* spillH   = (__half*)alloc((size_t)NB_NODES * 64 * 2);
    __half* spillQ   = (__half*)alloc((size_t)NB_NODES * 16 * 2);

    k1_hist<<<NBLK1, 256, 0, stream>>>(ei + NB_EDGES, hist, batch, gstart);
    k2a_scan<<<NBUCK, 512, 0, stream>>>(hist, total);
    k3_scatter<<<NBLK1, 256, 0, stream>>>(ei, hist, total, ebuf);
    k4_fine<<<NBUCK, 256, 0, stream>>>(ebuf, total, csr_src, rowptr, dinv);

    layer0_k<<<NB_GRAPHS, 512, 0, stream>>>(x, gstart, gn0w, gn0b, gn0a, dinv, y16, spill16f);
    fused_l1_k<<<NB_GRAPHS, 256, 0, stream>>>(y16, gstart, rowptr, csr_src, dinv,
                                              W1, b1, gn1w, gn1b, gn1a, W2, A, spillH, spillQ);
    fused_aggnorm_k<<<NB_GRAPHS, 256, 0, stream>>>(A, gstart, rowptr, csr_src, dinv,
                                                   b2, gn2w, gn2b, gn2a, W3, B, spillH);
    fused_aggpool_k<<<NB_GRAPHS, 256, 0, stream>>>(B, gstart, rowptr, csr_src, dinv,
                                                   b3, Wd, bd, Wo, bo, (float*)d_out);
}